// Round 2
// baseline (1106.440 us; speedup 1.0000x reference)
//
#include <hip/hip_runtime.h>
#include <hip/hip_bf16.h>
#include <math.h>

namespace {

constexpr int B_ = 2, P_ = 12, N_ = 170, DM_ = 64, H_ = 8, DK_ = 8, DH_ = 32, DF_ = 256;
constexpr int T_ = B_ * P_ * N_;        // 4080 tokens
constexpr int KTOT = (DH_ + 1) * DM_;   // 2112 (32 h-rows x 64 d + 64 bias rows)
constexpr float SQRT_DK = 2.8284271247461903f;

// ---------- meta hidden: hr = relu(c_x @ w1 + b1)  [T_,32] ----------
__global__ void k_hr(const float* __restrict__ c_x, const float* __restrict__ w1,
                     const float* __restrict__ b1, float* __restrict__ hr) {
    int idx = blockIdx.x * 256 + threadIdx.x;          // t*32 + j
    if (idx >= T_ * DH_) return;
    int t = idx / DH_, j = idx % DH_;
    float acc = b1[j];
    const float* cx = c_x + t * DM_;
    #pragma unroll
    for (int d = 0; d < DM_; ++d) acc += cx[d] * w1[d * DH_ + j];
    hr[idx] = fmaxf(acc, 0.f);
}

// ---------- fused meta+mhlin GEMM: qkv[t, m] = sum_k Z[t,k] * W2p[k,m] ----------
// Z[t, j*64+d] = hr[t,j]*xin[t,d] (j<32), = xin[t,d] (j==32, bias row)
// W2p[j*64+d, m] = w2[j, m*64+d] (j<32), = b2[m*64+d] (j==32)
// M=4080 (TM=32), N=192 (TN=64), K=2112 (chunk 16). 128 threads, 4x4 per thread.
__global__ __launch_bounds__(128) void k_meta_gemm(
    const float* __restrict__ hr, const float* __restrict__ xin,
    const float* __restrict__ w2, const float* __restrict__ b2,
    float* __restrict__ qkv) {
    __shared__ float Zs[16][33];
    __shared__ float Ws[16][65];
    const int t0 = blockIdx.x * 32;
    const int m0 = blockIdx.y * 64;
    const int tid = threadIdx.x;
    const int tx = tid & 15, ty = tid >> 4;   // tx: 16 m-groups of 4, ty: 8 t-groups of 4
    float acc[4][4] = {};
    for (int kc = 0; kc < KTOT; kc += 16) {
        __syncthreads();
        #pragma unroll
        for (int e = 0; e < 4; ++e) {          // stage Z: 512 elems
            int i = tid * 4 + e;
            int kk = i >> 5, tt = i & 31;
            int t = t0 + tt, k = kc + kk;
            int j = k >> 6, d = k & 63;
            float v = 0.f;
            if (t < T_) {
                float xv = xin[t * DM_ + d];
                v = (j < DH_) ? hr[t * DH_ + j] * xv : xv;
            }
            Zs[kk][tt] = v;
        }
        #pragma unroll
        for (int e = 0; e < 8; ++e) {          // stage W: 1024 elems
            int i = tid * 8 + e;
            int kk = i >> 6, mm = i & 63;
            int k = kc + kk, j = k >> 6, d = k & 63;
            int m = m0 + mm;
            Ws[kk][mm] = (j < DH_) ? w2[j * 12288 + m * 64 + d] : b2[m * 64 + d];
        }
        __syncthreads();
        #pragma unroll
        for (int kk = 0; kk < 16; ++kk) {
            float zr[4], wr[4];
            #pragma unroll
            for (int i = 0; i < 4; ++i) zr[i] = Zs[kk][ty * 4 + i];
            #pragma unroll
            for (int i = 0; i < 4; ++i) wr[i] = Ws[kk][tx * 4 + i];
            #pragma unroll
            for (int i = 0; i < 4; ++i)
                #pragma unroll
                for (int q = 0; q < 4; ++q) acc[i][q] += zr[i] * wr[q];
        }
    }
    #pragma unroll
    for (int i = 0; i < 4; ++i) {
        int t = t0 + ty * 4 + i;
        if (t >= T_) continue;
        #pragma unroll
        for (int q = 0; q < 4; ++q) qkv[t * 192 + m0 + tx * 4 + q] = acc[i][q];
    }
}

// ---------- retnet temporal retention ----------
// thread per (b,n,h,q); qkv layout [t][g*64 + h*8 + k], g=0:Q 1:K 2:V
__global__ void k_retnet(const float* __restrict__ qkv, const float* __restrict__ Dm,
                         float* __restrict__ att) {
    int idx = blockIdx.x * 256 + threadIdx.x;
    if (idx >= B_ * N_ * H_ * P_) return;
    int q = idx % P_;
    int h = (idx / P_) % H_;
    int n = (idx / (P_ * H_)) % N_;
    int b = idx / (P_ * H_ * N_);
    int tq = (b * P_ + q) * N_ + n;
    float Qv[8];
    #pragma unroll
    for (int k = 0; k < 8; ++k) Qv[k] = qkv[tq * 192 + h * 8 + k];
    float r[P_];
    float rsum = 0.f;
    for (int p = 0; p < P_; ++p) {
        int tp = (b * P_ + p) * N_ + n;
        float s = 0.f;
        #pragma unroll
        for (int k = 0; k < 8; ++k) s += Qv[k] * qkv[tp * 192 + 64 + h * 8 + k];
        s /= SQRT_DK;
        s *= Dm[(h * P_ + q) * P_ + p];
        r[p] = s; rsum += s;
    }
    float rs = fmaxf(fabsf(rsum), 1.0f);
    float acc[8] = {};
    for (int p = 0; p < P_; ++p) {
        float w = r[p] / rs;
        int tp = (b * P_ + p) * N_ + n;
        #pragma unroll
        for (int k = 0; k < 8; ++k) acc[k] += w * qkv[tp * 192 + 128 + h * 8 + k];
    }
    #pragma unroll
    for (int k = 0; k < 8; ++k) att[tq * 64 + h * 8 + k] = acc[k];
}

// ---------- temporal enc-dec attention (standard softmax over p) ----------
__global__ void k_temporal(const float* __restrict__ qkv, float* __restrict__ att) {
    int idx = blockIdx.x * 256 + threadIdx.x;
    if (idx >= B_ * N_ * H_ * P_) return;
    int q = idx % P_;
    int h = (idx / P_) % H_;
    int n = (idx / (P_ * H_)) % N_;
    int b = idx / (P_ * H_ * N_);
    int tq = (b * P_ + q) * N_ + n;
    float Qv[8];
    #pragma unroll
    for (int k = 0; k < 8; ++k) Qv[k] = qkv[tq * 192 + h * 8 + k];
    float s[P_]; float mx = -1e30f;
    for (int p = 0; p < P_; ++p) {
        int tp = (b * P_ + p) * N_ + n;
        float v = 0.f;
        #pragma unroll
        for (int k = 0; k < 8; ++k) v += Qv[k] * qkv[tp * 192 + 64 + h * 8 + k];
        v /= SQRT_DK;
        s[p] = v; mx = fmaxf(mx, v);
    }
    float den = 0.f; float acc[8] = {};
    for (int p = 0; p < P_; ++p) {
        float e = expf(s[p] - mx);
        den += e;
        int tp = (b * P_ + p) * N_ + n;
        #pragma unroll
        for (int k = 0; k < 8; ++k) acc[k] += e * qkv[tp * 192 + 128 + h * 8 + k];
    }
    float inv = 1.f / den;
    #pragma unroll
    for (int k = 0; k < 8; ++k) att[tq * 64 + h * 8 + k] = acc[k] * inv;
}

// ---------- adjacency-masked spatial attention (nozero softmax semantics) ----------
// block per (b,p,h); K/V staged in LDS; thread = query row i
__global__ __launch_bounds__(192) void k_spatial(const float* __restrict__ qkv,
                                                 const float* __restrict__ Tm, int adaptive,
                                                 float* __restrict__ att) {
    int blk = blockIdx.x;
    int h = blk % H_;
    int p = (blk / H_) % P_;
    int b = blk / (H_ * P_);
    __shared__ float Ks[N_][8], Vs[N_][8];
    for (int e = threadIdx.x; e < N_ * 8; e += 192) {
        int j = e >> 3, k = e & 7;
        int tj = (b * P_ + p) * N_ + j;
        Ks[j][k] = qkv[tj * 192 + 64 + h * 8 + k];
        Vs[j][k] = qkv[tj * 192 + 128 + h * 8 + k];
    }
    __syncthreads();
    int i = threadIdx.x;
    if (i >= N_) return;
    int ti = (b * P_ + p) * N_ + i;
    float Qv[8];
    #pragma unroll
    for (int k = 0; k < 8; ++k) Qv[k] = qkv[ti * 192 + h * 8 + k];
    const float* Trow = adaptive ? (Tm + ((size_t)(b * P_ + p) * N_ + i) * N_)
                                 : (Tm + (size_t)i * N_);
    // pass 1: row max over full row (masked entries are exactly 0 and DO enter the max)
    float mx = -1e30f;
    for (int j = 0; j < N_; ++j) {
        float tv = Trow[j];
        float s = 0.f;
        if (tv != 0.f) {
            #pragma unroll
            for (int k = 0; k < 8; ++k) s += Qv[k] * Ks[j][k];
            s /= SQRT_DK;
        }
        mx = fmaxf(mx, s);
    }
    // pass 2: e = exp(s-mx)*(s!=0); out = (1/(sum e + 1e-5)) * sum e*T_ij*V_j
    float den = 0.f; float acc[8] = {};
    for (int j = 0; j < N_; ++j) {
        float tv = Trow[j];
        if (tv == 0.f) continue;
        float s = 0.f;
        #pragma unroll
        for (int k = 0; k < 8; ++k) s += Qv[k] * Ks[j][k];
        s /= SQRT_DK;
        if (s == 0.f) continue;   // nozero mask
        float e = expf(s - mx);
        den += e;
        float w = e * tv;
        #pragma unroll
        for (int k = 0; k < 8; ++k) acc[k] += w * Vs[j][k];
    }
    float inv = 1.f / (den + 1e-5f);
    #pragma unroll
    for (int k = 0; k < 8; ++k) att[ti * 64 + h * 8 + k] = acc[k] * inv;
}

// ---------- gdc over G=8,C=8 for one output dim ----------
__device__ __forceinline__ float gdc8(const float* dv, const float* W1,
                                      const float* W2, int dm) {
    float a[8], s[8];
    #pragma unroll
    for (int g = 0; g < 8; ++g) {
        float aa = 0.f, ss = 0.f;
        #pragma unroll
        for (int c = 0; c < 8; ++c) {
            float d = dv[g * 8 + c];
            aa += d * W1[(g * 8 + c) * 64 + dm];
            ss += d * W2[(g * 8 + c) * 64 + dm];
        }
        a[g] = aa; s[g] = fmaxf(ss, 0.f);
    }
    float mx = s[0];
    #pragma unroll
    for (int g = 1; g < 8; ++g) mx = fmaxf(mx, s[g]);
    float den = 0.f, o = 0.f;
    #pragma unroll
    for (int g = 0; g < 8; ++g) { float e = expf(s[g] - mx); den += e; o += a[g] * e; }
    return o / den;
}

__device__ __forceinline__ float ln_out(float r, int dm, const float* g, const float* b) {
    float m = r, m2 = r * r;
    #pragma unroll
    for (int off = 32; off; off >>= 1) { m += __shfl_xor(m, off, 64); m2 += __shfl_xor(m2, off, 64); }
    m *= (1.f / 64.f); m2 *= (1.f / 64.f);
    float var = m2 - m * m;
    return (r - m) * rsqrtf(var + 1e-5f) * g[dm] + b[dm];
}

// ---------- fused gdc(H=8) + swish-gate + residual + LN (retnet & enc-dec stages) ----------
__global__ __launch_bounds__(64) void k_gsl(const float* __restrict__ att, const float* __restrict__ xin,
    const float* W1, const float* W2,
    const float* wg, const float* bg,
    const float* wo, const float* bo,
    const float* lng, const float* lnb, float* __restrict__ xout) {
    int t = blockIdx.x, dm = threadIdx.x;
    __shared__ float dv[64], xv[64], swv[64];
    dv[dm] = att[t * 64 + dm];
    xv[dm] = xin[t * 64 + dm];
    __syncthreads();
    float o = gdc8(dv, W1, W2, dm);
    float hg = bg[dm];
    #pragma unroll
    for (int d = 0; d < 64; ++d) hg += xv[d] * wg[d * 64 + dm];
    hg *= o;
    swv[dm] = hg / (1.f + expf(-hg));
    __syncthreads();
    float ov = bo[dm];
    #pragma unroll
    for (int d = 0; d < 64; ++d) ov += swv[d] * wo[d * 64 + dm];
    float r = ov + xv[dm];
    xout[t * 64 + dm] = ln_out(r, dm, lng, lnb);
}

// ---------- spatial stage tail: gdc0 + gdc1 + g2(G=2,C=64) + swish + LN ----------
__global__ __launch_bounds__(64) void k_spatial_fuse(
    const float* __restrict__ att0, const float* __restrict__ att1, const float* __restrict__ x1,
    const float* gs0_W1, const float* gs0_W2,
    const float* gs1_W1, const float* gs1_W2,
    const float* g2_W1, const float* g2_W2,
    const float* wg, const float* bg,
    const float* wo, const float* bo,
    const float* lng, const float* lnb, float* __restrict__ xout) {
    int t = blockIdx.x, dm = threadIdx.x;
    __shared__ float d0[64], d1[64], o0s[64], o1s[64], xv[64], swv[64];
    d0[dm] = att0[t * 64 + dm];
    d1[dm] = att1[t * 64 + dm];
    xv[dm] = x1[t * 64 + dm];
    __syncthreads();
    o0s[dm] = gdc8(d0, gs0_W1, gs0_W2, dm);
    o1s[dm] = gdc8(d1, gs1_W1, gs1_W2, dm);
    __syncthreads();
    float a0 = 0.f, s0 = 0.f, a1 = 0.f, s1 = 0.f;
    #pragma unroll
    for (int c = 0; c < 64; ++c) {
        a0 += o0s[c] * g2_W1[c * 64 + dm];
        s0 += o0s[c] * g2_W2[c * 64 + dm];
        a1 += o1s[c] * g2_W1[(64 + c) * 64 + dm];
        s1 += o1s[c] * g2_W2[(64 + c) * 64 + dm];
    }
    s0 = fmaxf(s0, 0.f); s1 = fmaxf(s1, 0.f);
    float mx = fmaxf(s0, s1);
    float e0 = expf(s0 - mx), e1 = expf(s1 - mx);
    float o = (a0 * e0 + a1 * e1) / (e0 + e1);
    float hg = bg[dm];
    #pragma unroll
    for (int d = 0; d < 64; ++d) hg += xv[d] * wg[d * 64 + dm];
    hg *= o;
    swv[dm] = hg / (1.f + expf(-hg));
    __syncthreads();
    float ov = bo[dm];
    #pragma unroll
    for (int d = 0; d < 64; ++d) ov += swv[d] * wo[d * 64 + dm];
    float r = ov + xv[dm];
    xout[t * 64 + dm] = ln_out(r, dm, lng, lnb);
}

// ---------- q/k/v projections for enc-dec stage ----------
__global__ __launch_bounds__(64) void k_qkvproj(const float* __restrict__ x2,
    const float* __restrict__ enc,
    const float* wq, const float* wk, const float* wv,
    float* __restrict__ qkv) {
    int t = blockIdx.x, dm = threadIdx.x;
    __shared__ float xv[64], ev[64];
    xv[dm] = x2[t * 64 + dm];
    ev[dm] = enc[t * 64 + dm];
    __syncthreads();
    float aq = 0.f, ak = 0.f, av = 0.f;
    #pragma unroll
    for (int d = 0; d < 64; ++d) {
        aq += xv[d] * wq[d * 64 + dm];
        ak += ev[d] * wk[d * 64 + dm];
        av += ev[d] * wv[d * 64 + dm];
    }
    qkv[t * 192 + dm] = aq;
    qkv[t * 192 + 64 + dm] = ak;
    qkv[t * 192 + 128 + dm] = av;
}

// ---------- FFN + residual + LN -> fp32 output ----------
__global__ __launch_bounds__(64) void k_ffn(const float* __restrict__ x3,
    const float* w1, const float* b1,
    const float* w2, const float* b2,
    const float* lng, const float* lnb,
    float* __restrict__ out) {
    int t = blockIdx.x, dm = threadIdx.x;
    __shared__ float xv[64], hv[256];
    xv[dm] = x3[t * 64 + dm];
    __syncthreads();
    #pragma unroll
    for (int e = 0; e < 4; ++e) {
        int j = e * 64 + dm;
        float a = b1[j];
        #pragma unroll
        for (int d = 0; d < 64; ++d) a += xv[d] * w1[d * 256 + j];
        hv[j] = fmaxf(a, 0.f);
    }
    __syncthreads();
    float a = b2[dm];
    for (int j = 0; j < 256; ++j) a += hv[j] * w2[j * 64 + dm];
    float r = a + xv[dm];
    out[t * 64 + dm] = ln_out(r, dm, lng, lnb);
}

} // namespace

extern "C" void kernel_launch(void* const* d_in, const int* in_sizes, int n_in,
                              void* d_out, int out_size, void* d_ws, size_t ws_size,
                              hipStream_t stream) {
    (void)in_sizes; (void)n_in; (void)out_size; (void)ws_size;
    const float* x    = (const float*)d_in[0];
    const float* c_x  = (const float*)d_in[1];
    const float* enc  = (const float*)d_in[2];
    const float* Tm   = (const float*)d_in[3];
    const float* Am   = (const float*)d_in[4];
    const float* Dm   = (const float*)d_in[5];
    const float* mr_w1 = (const float*)d_in[6];
    const float* mr_b1 = (const float*)d_in[7];
    const float* mr_w2 = (const float*)d_in[8];
    const float* mr_b2 = (const float*)d_in[9];
    const float* ms0_w1 = (const float*)d_in[10];
    const float* ms0_b1 = (const float*)d_in[11];
    const float* ms0_w2 = (const float*)d_in[12];
    const float* ms0_b2 = (const float*)d_in[13];
    const float* ms1_w1 = (const float*)d_in[14];
    const float* ms1_b1 = (const float*)d_in[15];
    const float* ms1_w2 = (const float*)d_in[16];
    const float* ms1_b2 = (const float*)d_in[17];
    const float* gr_W1 = (const float*)d_in[18];
    const float* gr_W2 = (const float*)d_in[19];
    const float* gs0_W1 = (const float*)d_in[20];
    const float* gs0_W2 = (const float*)d_in[21];
    const float* gs1_W1 = (const float*)d_in[22];
    const float* gs1_W2 = (const float*)d_in[23];
    const float* g2_W1 = (const float*)d_in[24];
    const float* g2_W2 = (const float*)d_in[25];
    const float* ge_W1 = (const float*)d_in[26];
    const float* ge_W2 = (const float*)d_in[27];
    const float* swr_wg = (const float*)d_in[28];
    const float* swr_bg = (const float*)d_in[29];
    const float* swr_wo = (const float*)d_in[30];
    const float* swr_bo = (const float*)d_in[31];
    const float* sws_wg = (const float*)d_in[32];
    const float* sws_bg = (const float*)d_in[33];
    const float* sws_wo = (const float*)d_in[34];
    const float* sws_bo = (const float*)d_in[35];
    const float* swe_wg = (const float*)d_in[36];
    const float* swe_bg = (const float*)d_in[37];
    const float* swe_wo = (const float*)d_in[38];
    const float* swe_bo = (const float*)d_in[39];
    const float* lnr_g = (const float*)d_in[40];
    const float* lnr_b = (const float*)d_in[41];
    const float* lns_g = (const float*)d_in[42];
    const float* lns_b = (const float*)d_in[43];
    const float* lne_g = (const float*)d_in[44];
    const float* lne_b = (const float*)d_in[45];
    const float* lnf_g = (const float*)d_in[46];
    const float* lnf_b = (const float*)d_in[47];
    const float* wq = (const float*)d_in[48];
    const float* wk = (const float*)d_in[49];
    const float* wv = (const float*)d_in[50];
    const float* f_w1 = (const float*)d_in[51];
    const float* f_b1 = (const float*)d_in[52];
    const float* f_w2 = (const float*)d_in[53];
    const float* f_b2 = (const float*)d_in[54];

    // workspace layout (fp32), ~12 MB total
    float* ws   = (float*)d_ws;
    float* hr   = ws;                 // 130560
    float* qkva = hr   + T_ * DH_;    // 783360
    float* qkvb = qkva + T_ * 192;    // 783360
    float* atta = qkvb + T_ * 192;    // 261120
    float* attb = atta + T_ * DM_;    // 261120
    float* x1f  = attb + T_ * DM_;    // 261120
    float* x2f  = x1f  + T_ * DM_;    // 261120
    float* x3f  = x2f  + T_ * DM_;    // 261120

    dim3 gemm_grid((T_ + 31) / 32, 3);

    // ---- stage 1: retnet retention ----
    k_hr<<<(T_ * DH_ + 255) / 256, 256, 0, stream>>>(c_x, mr_w1, mr_b1, hr);
    k_meta_gemm<<<gemm_grid, 128, 0, stream>>>(hr, x, mr_w2, mr_b2, qkva);
    k_retnet<<<(B_ * N_ * H_ * P_ + 255) / 256, 256, 0, stream>>>(qkva, Dm, atta);
    k_gsl<<<T_, 64, 0, stream>>>(atta, x, gr_W1, gr_W2, swr_wg, swr_bg, swr_wo, swr_bo,
                                 lnr_g, lnr_b, x1f);

    // ---- stage 2: spatial (predefined T + adaptive A) ----
    k_hr<<<(T_ * DH_ + 255) / 256, 256, 0, stream>>>(c_x, ms0_w1, ms0_b1, hr);
    k_meta_gemm<<<gemm_grid, 128, 0, stream>>>(hr, x1f, ms0_w2, ms0_b2, qkva);
    k_hr<<<(T_ * DH_ + 255) / 256, 256, 0, stream>>>(c_x, ms1_w1, ms1_b1, hr);
    k_meta_gemm<<<gemm_grid, 128, 0, stream>>>(hr, x1f, ms1_w2, ms1_b2, qkvb);
    k_spatial<<<B_ * P_ * H_, 192, 0, stream>>>(qkva, Tm, 0, atta);
    k_spatial<<<B_ * P_ * H_, 192, 0, stream>>>(qkvb, Am, 1, attb);
    k_spatial_fuse<<<T_, 64, 0, stream>>>(atta, attb, x1f, gs0_W1, gs0_W2, gs1_W1, gs1_W2,
                                          g2_W1, g2_W2, sws_wg, sws_bg, sws_wo, sws_bo,
                                          lns_g, lns_b, x2f);

    // ---- stage 3: temporal encoder-decoder attention ----
    k_qkvproj<<<T_, 64, 0, stream>>>(x2f, enc, wq, wk, wv, qkva);
    k_temporal<<<(B_ * N_ * H_ * P_ + 255) / 256, 256, 0, stream>>>(qkva, atta);
    k_gsl<<<T_, 64, 0, stream>>>(atta, x2f, ge_W1, ge_W2, swe_wg, swe_bg, swe_wo, swe_bo,
                                 lne_g, lne_b, x3f);

    // ---- stage 4: FFN ----
    k_ffn<<<T_, 64, 0, stream>>>(x3f, f_w1, f_b1, f_w2, f_b2, lnf_g, lnf_b, (float*)d_out);
}

// Round 3
// 511.576 us; speedup vs baseline: 2.1628x; 2.1628x over previous
//
#include <hip/hip_runtime.h>
#include <hip/hip_bf16.h>
#include <math.h>

namespace {

constexpr int B_ = 2, P_ = 12, N_ = 170, DM_ = 64, H_ = 8, DK_ = 8, DH_ = 32, DF_ = 256;
constexpr int T_ = B_ * P_ * N_;        // 4080 tokens
constexpr float SQRT_DK = 2.8284271247461903f;

typedef __attribute__((ext_vector_type(4))) short short4v;
typedef __attribute__((ext_vector_type(8))) short short8v;
typedef __attribute__((ext_vector_type(4))) float float4v;

// float -> bf16 bits, round-to-nearest-even
__device__ __forceinline__ unsigned short f2bf(float x) {
    union { float f; unsigned int u; } c; c.f = x;
    unsigned int r = (c.u + 0x7FFFu + ((c.u >> 16) & 1u)) >> 16;
    return (unsigned short)r;
}

// ---------- meta hidden: hr = relu(c_x @ w1 + b1)  [T_,32] ----------
__global__ void k_hr(const float* __restrict__ c_x, const float* __restrict__ w1,
                     const float* __restrict__ b1, float* __restrict__ hr) {
    int idx = blockIdx.x * 256 + threadIdx.x;          // t*32 + j
    if (idx >= T_ * DH_) return;
    int t = idx / DH_, j = idx % DH_;
    float acc = b1[j];
    const float* cx = c_x + t * DM_;
    #pragma unroll
    for (int d = 0; d < DM_; ++d) acc += cx[d] * w1[d * DH_ + j];
    hr[idx] = fmaxf(acc, 0.f);
}

// ---------- fused meta+mhlin GEMM via bf16 MFMA ----------
// qkv[t,m] = sum_{k} Z[t,k] * W2p[k,m], K = 33*64 = 2112 (66 chunks of 32)
// Z[t, j*64+d] = hr[t,j]*xin[t,d] (j<32), = xin[t,d] (bias row j==32)
// W2p[j*64+d, m] = w2[j, m*64+d] (j<32), = b2[m*64+d] (j==32)
// Tile 32(t) x 32(m), 128 threads (2 waves); mfma_f32_16x16x32_bf16.
// A-frag: row m=lane&15, k=quad*8+j; B-frag: col n=lane&15, same k;
// D: col(n)=lane&15, row(m)=quad*4+reg  [verified layout, learn_hip m89/m91]
__global__ __launch_bounds__(128) void k_meta_mfma(
    const float* __restrict__ hrA, const float* __restrict__ hrB,
    const float* __restrict__ xin,
    const float* __restrict__ w2A, const float* __restrict__ b2A,
    const float* __restrict__ w2B, const float* __restrict__ b2B,
    float* __restrict__ outA, float* __restrict__ outB) {
    const int bz = blockIdx.z;
    const float* hr = bz ? hrB : hrA;
    const float* w2 = bz ? w2B : w2A;
    const float* b2 = bz ? b2B : b2A;
    float* out = bz ? outB : outA;

    const int t0 = blockIdx.x * 32;
    const int m0 = blockIdx.y * 32;
    const int tid = threadIdx.x;

    __shared__ unsigned short Zs[32][40];   // [t-local][k-local], pad 32->40 shorts (80B rows)
    __shared__ unsigned short Ws[32][40];   // [n-local][k-local]

    const int wv = tid >> 6;       // wave 0/1 -> t-rows [wv*16, wv*16+16)
    const int lane = tid & 63;
    const int l15 = lane & 15;
    const int quad = lane >> 4;

    const int row = tid >> 2;      // staging row 0..31
    const int q2 = (tid & 3) * 2;  // two float4 per thread: q2, q2+1  (of 8 per row)

    const int tA = t0 + row;
    const bool tok = (tA < T_);

    float4v acc0 = {0.f, 0.f, 0.f, 0.f};
    float4v acc1 = {0.f, 0.f, 0.f, 0.f};

    for (int kc = 0; kc < 66; ++kc) {
        const int j = kc >> 1;
        const int d0 = (kc & 1) * 32;
        const float* wrow = (j < DH_) ? (w2 + j * 12288) : b2;

        __syncthreads();
        // stage A (Z tile): Zs[row][k] = f * x[tA, d0+k]
        {
            float f = 0.f;
            if (tok) f = (j < DH_) ? hr[tA * DH_ + j] : 1.f;
            const float* xp = xin + (tok ? tA : 0) * DM_ + d0;
            #pragma unroll
            for (int e = 0; e < 2; ++e) {
                int qq = q2 + e;
                float4v xv = *(const float4v*)(xp + qq * 4);
                short4v z;
                z.x = (short)f2bf(f * xv.x);
                z.y = (short)f2bf(f * xv.y);
                z.z = (short)f2bf(f * xv.z);
                z.w = (short)f2bf(f * xv.w);
                *(short4v*)&Zs[row][qq * 4] = z;
            }
        }
        // stage B (W tile): Ws[row][k] = wrow[(m0+row)*64 + d0 + k]
        {
            const float* wp = wrow + (m0 + row) * 64 + d0;
            #pragma unroll
            for (int e = 0; e < 2; ++e) {
                int qq = q2 + e;
                float4v wvv = *(const float4v*)(wp + qq * 4);
                short4v z;
                z.x = (short)f2bf(wvv.x);
                z.y = (short)f2bf(wvv.y);
                z.z = (short)f2bf(wvv.z);
                z.w = (short)f2bf(wvv.w);
                *(short4v*)&Ws[row][qq * 4] = z;
            }
        }
        __syncthreads();

        short8v a  = *(const short8v*)&Zs[wv * 16 + l15][quad * 8];
        short8v b0 = *(const short8v*)&Ws[l15][quad * 8];
        short8v b1 = *(const short8v*)&Ws[16 + l15][quad * 8];
        acc0 = __builtin_amdgcn_mfma_f32_16x16x32_bf16(a, b0, acc0, 0, 0, 0);
        acc1 = __builtin_amdgcn_mfma_f32_16x16x32_bf16(a, b1, acc1, 0, 0, 0);
    }

    const int col = m0 + l15;
    #pragma unroll
    for (int r = 0; r < 4; ++r) {
        int t = t0 + wv * 16 + quad * 4 + r;
        if (t < T_) {
            out[t * 192 + col] = acc0[r];
            out[t * 192 + col + 16] = acc1[r];
        }
    }
}

// ---------- retnet temporal retention ----------
__global__ void k_retnet(const float* __restrict__ qkv, const float* __restrict__ Dm,
                         float* __restrict__ att) {
    int idx = blockIdx.x * 256 + threadIdx.x;
    if (idx >= B_ * N_ * H_ * P_) return;
    int q = idx % P_;
    int h = (idx / P_) % H_;
    int n = (idx / (P_ * H_)) % N_;
    int b = idx / (P_ * H_ * N_);
    int tq = (b * P_ + q) * N_ + n;
    float Qv[8];
    #pragma unroll
    for (int k = 0; k < 8; ++k) Qv[k] = qkv[tq * 192 + h * 8 + k];
    float r[P_];
    float rsum = 0.f;
    for (int p = 0; p < P_; ++p) {
        int tp = (b * P_ + p) * N_ + n;
        float s = 0.f;
        #pragma unroll
        for (int k = 0; k < 8; ++k) s += Qv[k] * qkv[tp * 192 + 64 + h * 8 + k];
        s /= SQRT_DK;
        s *= Dm[(h * P_ + q) * P_ + p];
        r[p] = s; rsum += s;
    }
    float rs = fmaxf(fabsf(rsum), 1.0f);
    float acc[8] = {};
    for (int p = 0; p < P_; ++p) {
        float w = r[p] / rs;
        int tp = (b * P_ + p) * N_ + n;
        #pragma unroll
        for (int k = 0; k < 8; ++k) acc[k] += w * qkv[tp * 192 + 128 + h * 8 + k];
    }
    #pragma unroll
    for (int k = 0; k < 8; ++k) att[tq * 64 + h * 8 + k] = acc[k];
}

// ---------- temporal enc-dec attention (standard softmax over p) ----------
__global__ void k_temporal(const float* __restrict__ qkv, float* __restrict__ att) {
    int idx = blockIdx.x * 256 + threadIdx.x;
    if (idx >= B_ * N_ * H_ * P_) return;
    int q = idx % P_;
    int h = (idx / P_) % H_;
    int n = (idx / (P_ * H_)) % N_;
    int b = idx / (P_ * H_ * N_);
    int tq = (b * P_ + q) * N_ + n;
    float Qv[8];
    #pragma unroll
    for (int k = 0; k < 8; ++k) Qv[k] = qkv[tq * 192 + h * 8 + k];
    float s[P_]; float mx = -1e30f;
    for (int p = 0; p < P_; ++p) {
        int tp = (b * P_ + p) * N_ + n;
        float v = 0.f;
        #pragma unroll
        for (int k = 0; k < 8; ++k) v += Qv[k] * qkv[tp * 192 + 64 + h * 8 + k];
        v /= SQRT_DK;
        s[p] = v; mx = fmaxf(mx, v);
    }
    float den = 0.f; float acc[8] = {};
    for (int p = 0; p < P_; ++p) {
        float e = expf(s[p] - mx);
        den += e;
        int tp = (b * P_ + p) * N_ + n;
        #pragma unroll
        for (int k = 0; k < 8; ++k) acc[k] += e * qkv[tp * 192 + 128 + h * 8 + k];
    }
    float inv = 1.f / den;
    #pragma unroll
    for (int k = 0; k < 8; ++k) att[tq * 64 + h * 8 + k] = acc[k] * inv;
}

// ---------- adjacency-masked spatial attention (nozero softmax semantics) ----------
__global__ __launch_bounds__(192) void k_spatial(const float* __restrict__ qkv,
                                                 const float* __restrict__ Tm, int adaptive,
                                                 float* __restrict__ att) {
    int blk = blockIdx.x;
    int h = blk % H_;
    int p = (blk / H_) % P_;
    int b = blk / (H_ * P_);
    __shared__ float Ks[N_][8], Vs[N_][8];
    for (int e = threadIdx.x; e < N_ * 8; e += 192) {
        int j = e >> 3, k = e & 7;
        int tj = (b * P_ + p) * N_ + j;
        Ks[j][k] = qkv[tj * 192 + 64 + h * 8 + k];
        Vs[j][k] = qkv[tj * 192 + 128 + h * 8 + k];
    }
    __syncthreads();
    int i = threadIdx.x;
    if (i >= N_) return;
    int ti = (b * P_ + p) * N_ + i;
    float Qv[8];
    #pragma unroll
    for (int k = 0; k < 8; ++k) Qv[k] = qkv[ti * 192 + h * 8 + k];
    const float* Trow = adaptive ? (Tm + ((size_t)(b * P_ + p) * N_ + i) * N_)
                                 : (Tm + (size_t)i * N_);
    float mx = -1e30f;
    for (int j = 0; j < N_; ++j) {
        float tv = Trow[j];
        float s = 0.f;
        if (tv != 0.f) {
            #pragma unroll
            for (int k = 0; k < 8; ++k) s += Qv[k] * Ks[j][k];
            s /= SQRT_DK;
        }
        mx = fmaxf(mx, s);
    }
    float den = 0.f; float acc[8] = {};
    for (int j = 0; j < N_; ++j) {
        float tv = Trow[j];
        if (tv == 0.f) continue;
        float s = 0.f;
        #pragma unroll
        for (int k = 0; k < 8; ++k) s += Qv[k] * Ks[j][k];
        s /= SQRT_DK;
        if (s == 0.f) continue;   // nozero mask
        float e = expf(s - mx);
        den += e;
        float w = e * tv;
        #pragma unroll
        for (int k = 0; k < 8; ++k) acc[k] += w * Vs[j][k];
    }
    float inv = 1.f / (den + 1e-5f);
    #pragma unroll
    for (int k = 0; k < 8; ++k) att[ti * 64 + h * 8 + k] = acc[k] * inv;
}

// ---------- gdc over G=8,C=8 for one output dim ----------
__device__ __forceinline__ float gdc8(const float* dv, const float* W1,
                                      const float* W2, int dm) {
    float a[8], s[8];
    #pragma unroll
    for (int g = 0; g < 8; ++g) {
        float aa = 0.f, ss = 0.f;
        #pragma unroll
        for (int c = 0; c < 8; ++c) {
            float d = dv[g * 8 + c];
            aa += d * W1[(g * 8 + c) * 64 + dm];
            ss += d * W2[(g * 8 + c) * 64 + dm];
        }
        a[g] = aa; s[g] = fmaxf(ss, 0.f);
    }
    float mx = s[0];
    #pragma unroll
    for (int g = 1; g < 8; ++g) mx = fmaxf(mx, s[g]);
    float den = 0.f, o = 0.f;
    #pragma unroll
    for (int g = 0; g < 8; ++g) { float e = expf(s[g] - mx); den += e; o += a[g] * e; }
    return o / den;
}

__device__ __forceinline__ float ln_out(float r, int dm, const float* g, const float* b) {
    float m = r, m2 = r * r;
    #pragma unroll
    for (int off = 32; off; off >>= 1) { m += __shfl_xor(m, off, 64); m2 += __shfl_xor(m2, off, 64); }
    m *= (1.f / 64.f); m2 *= (1.f / 64.f);
    float var = m2 - m * m;
    return (r - m) * rsqrtf(var + 1e-5f) * g[dm] + b[dm];
}

// ---------- fused gdc(H=8) + swish-gate + residual + LN ----------
__global__ __launch_bounds__(64) void k_gsl(const float* __restrict__ att, const float* __restrict__ xin,
    const float* W1, const float* W2,
    const float* wg, const float* bg,
    const float* wo, const float* bo,
    const float* lng, const float* lnb, float* __restrict__ xout) {
    int t = blockIdx.x, dm = threadIdx.x;
    __shared__ float dv[64], xv[64], swv[64];
    dv[dm] = att[t * 64 + dm];
    xv[dm] = xin[t * 64 + dm];
    __syncthreads();
    float o = gdc8(dv, W1, W2, dm);
    float hg = bg[dm];
    #pragma unroll
    for (int d = 0; d < 64; ++d) hg += xv[d] * wg[d * 64 + dm];
    hg *= o;
    swv[dm] = hg / (1.f + expf(-hg));
    __syncthreads();
    float ov = bo[dm];
    #pragma unroll
    for (int d = 0; d < 64; ++d) ov += swv[d] * wo[d * 64 + dm];
    float r = ov + xv[dm];
    xout[t * 64 + dm] = ln_out(r, dm, lng, lnb);
}

// ---------- spatial stage tail: gdc0 + gdc1 + g2(G=2,C=64) + swish + LN ----------
__global__ __launch_bounds__(64) void k_spatial_fuse(
    const float* __restrict__ att0, const float* __restrict__ att1, const float* __restrict__ x1,
    const float* gs0_W1, const float* gs0_W2,
    const float* gs1_W1, const float* gs1_W2,
    const float* g2_W1, const float* g2_W2,
    const float* wg, const float* bg,
    const float* wo, const float* bo,
    const float* lng, const float* lnb, float* __restrict__ xout) {
    int t = blockIdx.x, dm = threadIdx.x;
    __shared__ float d0[64], d1[64], o0s[64], o1s[64], xv[64], swv[64];
    d0[dm] = att0[t * 64 + dm];
    d1[dm] = att1[t * 64 + dm];
    xv[dm] = x1[t * 64 + dm];
    __syncthreads();
    o0s[dm] = gdc8(d0, gs0_W1, gs0_W2, dm);
    o1s[dm] = gdc8(d1, gs1_W1, gs1_W2, dm);
    __syncthreads();
    float a0 = 0.f, s0 = 0.f, a1 = 0.f, s1 = 0.f;
    #pragma unroll
    for (int c = 0; c < 64; ++c) {
        a0 += o0s[c] * g2_W1[c * 64 + dm];
        s0 += o0s[c] * g2_W2[c * 64 + dm];
        a1 += o1s[c] * g2_W1[(64 + c) * 64 + dm];
        s1 += o1s[c] * g2_W2[(64 + c) * 64 + dm];
    }
    s0 = fmaxf(s0, 0.f); s1 = fmaxf(s1, 0.f);
    float mx = fmaxf(s0, s1);
    float e0 = expf(s0 - mx), e1 = expf(s1 - mx);
    float o = (a0 * e0 + a1 * e1) / (e0 + e1);
    float hg = bg[dm];
    #pragma unroll
    for (int d = 0; d < 64; ++d) hg += xv[d] * wg[d * 64 + dm];
    hg *= o;
    swv[dm] = hg / (1.f + expf(-hg));
    __syncthreads();
    float ov = bo[dm];
    #pragma unroll
    for (int d = 0; d < 64; ++d) ov += swv[d] * wo[d * 64 + dm];
    float r = ov + xv[dm];
    xout[t * 64 + dm] = ln_out(r, dm, lng, lnb);
}

// ---------- q/k/v projections for enc-dec stage ----------
__global__ __launch_bounds__(64) void k_qkvproj(const float* __restrict__ x2,
    const float* __restrict__ enc,
    const float* wq, const float* wk, const float* wv,
    float* __restrict__ qkv) {
    int t = blockIdx.x, dm = threadIdx.x;
    __shared__ float xv[64], ev[64];
    xv[dm] = x2[t * 64 + dm];
    ev[dm] = enc[t * 64 + dm];
    __syncthreads();
    float aq = 0.f, ak = 0.f, av = 0.f;
    #pragma unroll
    for (int d = 0; d < 64; ++d) {
        aq += xv[d] * wq[d * 64 + dm];
        ak += ev[d] * wk[d * 64 + dm];
        av += ev[d] * wv[d * 64 + dm];
    }
    qkv[t * 192 + dm] = aq;
    qkv[t * 192 + 64 + dm] = ak;
    qkv[t * 192 + 128 + dm] = av;
}

// ---------- FFN + residual + LN -> fp32 output ----------
__global__ __launch_bounds__(64) void k_ffn(const float* __restrict__ x3,
    const float* w1, const float* b1,
    const float* w2, const float* b2,
    const float* lng, const float* lnb,
    float* __restrict__ out) {
    int t = blockIdx.x, dm = threadIdx.x;
    __shared__ float xv[64], hv[256];
    xv[dm] = x3[t * 64 + dm];
    __syncthreads();
    #pragma unroll
    for (int e = 0; e < 4; ++e) {
        int j = e * 64 + dm;
        float a = b1[j];
        #pragma unroll
        for (int d = 0; d < 64; ++d) a += xv[d] * w1[d * 256 + j];
        hv[j] = fmaxf(a, 0.f);
    }
    __syncthreads();
    float a = b2[dm];
    for (int j = 0; j < 256; ++j) a += hv[j] * w2[j * 64 + dm];
    float r = a + xv[dm];
    out[t * 64 + dm] = ln_out(r, dm, lng, lnb);
}

} // namespace

extern "C" void kernel_launch(void* const* d_in, const int* in_sizes, int n_in,
                              void* d_out, int out_size, void* d_ws, size_t ws_size,
                              hipStream_t stream) {
    (void)in_sizes; (void)n_in; (void)out_size; (void)ws_size;
    const float* x    = (const float*)d_in[0];
    const float* c_x  = (const float*)d_in[1];
    const float* enc  = (const float*)d_in[2];
    const float* Tm   = (const float*)d_in[3];
    const float* Am   = (const float*)d_in[4];
    const float* Dm   = (const float*)d_in[5];
    const float* mr_w1 = (const float*)d_in[6];
    const float* mr_b1 = (const float*)d_in[7];
    const float* mr_w2 = (const float*)d_in[8];
    const float* mr_b2 = (const float*)d_in[9];
    const float* ms0_w1 = (const float*)d_in[10];
    const float* ms0_b1 = (const float*)d_in[11];
    const float* ms0_w2 = (const float*)d_in[12];
    const float* ms0_b2 = (const float*)d_in[13];
    const float* ms1_w1 = (const float*)d_in[14];
    const float* ms1_b1 = (const float*)d_in[15];
    const float* ms1_w2 = (const float*)d_in[16];
    const float* ms1_b2 = (const float*)d_in[17];
    const float* gr_W1 = (const float*)d_in[18];
    const float* gr_W2 = (const float*)d_in[19];
    const float* gs0_W1 = (const float*)d_in[20];
    const float* gs0_W2 = (const float*)d_in[21];
    const float* gs1_W1 = (const float*)d_in[22];
    const float* gs1_W2 = (const float*)d_in[23];
    const float* g2_W1 = (const float*)d_in[24];
    const float* g2_W2 = (const float*)d_in[25];
    const float* ge_W1 = (const float*)d_in[26];
    const float* ge_W2 = (const float*)d_in[27];
    const float* swr_wg = (const float*)d_in[28];
    const float* swr_bg = (const float*)d_in[29];
    const float* swr_wo = (const float*)d_in[30];
    const float* swr_bo = (const float*)d_in[31];
    const float* sws_wg = (const float*)d_in[32];
    const float* sws_bg = (const float*)d_in[33];
    const float* sws_wo = (const float*)d_in[34];
    const float* sws_bo = (const float*)d_in[35];
    const float* swe_wg = (const float*)d_in[36];
    const float* swe_bg = (const float*)d_in[37];
    const float* swe_wo = (const float*)d_in[38];
    const float* swe_bo = (const float*)d_in[39];
    const float* lnr_g = (const float*)d_in[40];
    const float* lnr_b = (const float*)d_in[41];
    const float* lns_g = (const float*)d_in[42];
    const float* lns_b = (const float*)d_in[43];
    const float* lne_g = (const float*)d_in[44];
    const float* lne_b = (const float*)d_in[45];
    const float* lnf_g = (const float*)d_in[46];
    const float* lnf_b = (const float*)d_in[47];
    const float* wq = (const float*)d_in[48];
    const float* wk = (const float*)d_in[49];
    const float* wv = (const float*)d_in[50];
    const float* f_w1 = (const float*)d_in[51];
    const float* f_b1 = (const float*)d_in[52];
    const float* f_w2 = (const float*)d_in[53];
    const float* f_b2 = (const float*)d_in[54];

    // workspace layout (fp32), ~13 MB total
    float* ws   = (float*)d_ws;
    float* hr   = ws;                 // 130560
    float* hr2  = hr   + T_ * DH_;    // 130560
    float* qkva = hr2  + T_ * DH_;    // 783360
    float* qkvb = qkva + T_ * 192;    // 783360
    float* atta = qkvb + T_ * 192;    // 261120
    float* attb = atta + T_ * DM_;    // 261120
    float* x1f  = attb + T_ * DM_;    // 261120
    float* x2f  = x1f  + T_ * DM_;    // 261120
    float* x3f  = x2f  + T_ * DM_;    // 261120

    dim3 g1(128, 6, 1), g2g(128, 6, 2);

    // ---- stage 1: retnet retention ----
    k_hr<<<(T_ * DH_ + 255) / 256, 256, 0, stream>>>(c_x, mr_w1, mr_b1, hr);
    k_meta_mfma<<<g1, 128, 0, stream>>>(hr, hr, x, mr_w2, mr_b2, mr_w2, mr_b2, qkva, qkva);
    k_retnet<<<(B_ * N_ * H_ * P_ + 255) / 256, 256, 0, stream>>>(qkva, Dm, atta);
    k_gsl<<<T_, 64, 0, stream>>>(atta, x, gr_W1, gr_W2, swr_wg, swr_bg, swr_wo, swr_bo,
                                 lnr_g, lnr_b, x1f);

    // ---- stage 2: spatial (predefined T + adaptive A), batched meta GEMMs ----
    k_hr<<<(T_ * DH_ + 255) / 256, 256, 0, stream>>>(c_x, ms0_w1, ms0_b1, hr);
    k_hr<<<(T_ * DH_ + 255) / 256, 256, 0, stream>>>(c_x, ms1_w1, ms1_b1, hr2);
    k_meta_mfma<<<g2g, 128, 0, stream>>>(hr, hr2, x1f, ms0_w2, ms0_b2, ms1_w2, ms1_b2,
                                         qkva, qkvb);
    k_spatial<<<B_ * P_ * H_, 192, 0, stream>>>(qkva, Tm, 0, atta);
    k_spatial<<<B_ * P_ * H_, 192, 0, stream>>>(qkvb, Am, 1, attb);
    k_spatial_fuse<<<T_, 64, 0, stream>>>(atta, attb, x1f, gs0_W1, gs0_W2, gs1_W1, gs1_W2,
                                          g2_W1, g2_W2, sws_wg, sws_bg, sws_wo, sws_bo,
                                          lns_g, lns_b, x2f);

    // ---- stage 3: temporal encoder-decoder attention ----
    k_qkvproj<<<T_, 64, 0, stream>>>(x2f, enc, wq, wk, wv, qkva);
    k_temporal<<<(B_ * N_ * H_ * P_ + 255) / 256, 256, 0, stream>>>(qkva, atta);
    k_gsl<<<T_, 64, 0, stream>>>(atta, x2f, ge_W1, ge_W2, swe_wg, swe_bg, swe_wo, swe_bo,
                                 lne_g, lne_b, x3f);

    // ---- stage 4: FFN ----
    k_ffn<<<T_, 64, 0, stream>>>(x3f, f_w1, f_b1, f_w2, f_b2, lnf_g, lnf_b, (float*)d_out);
}

// Round 4
// 508.940 us; speedup vs baseline: 2.1740x; 1.0052x over previous
//
#include <hip/hip_runtime.h>
#include <hip/hip_bf16.h>
#include <math.h>

namespace {

constexpr int B_ = 2, P_ = 12, N_ = 170, DM_ = 64, H_ = 8, DK_ = 8, DH_ = 32, DF_ = 256;
constexpr int T_ = B_ * P_ * N_;        // 4080 tokens
constexpr float SQRT_DK = 2.8284271247461903f;

typedef __attribute__((ext_vector_type(4))) short short4v;
typedef __attribute__((ext_vector_type(8))) short short8v;
typedef __attribute__((ext_vector_type(4))) float float4v;

// float -> bf16 bits, round-to-nearest-even
__device__ __forceinline__ unsigned short f2bf(float x) {
    union { float f; unsigned int u; } c; c.f = x;
    unsigned int r = (c.u + 0x7FFFu + ((c.u >> 16) & 1u)) >> 16;
    return (unsigned short)r;
}

// ---------- meta hidden (x3 batched): hr = relu(c_x @ w1 + b1)  [T_,32] ----------
__global__ void k_hr3(const float* __restrict__ c_x,
                      const float* __restrict__ w1a, const float* __restrict__ b1a,
                      const float* __restrict__ w1b, const float* __restrict__ b1b,
                      const float* __restrict__ w1c, const float* __restrict__ b1c,
                      float* __restrict__ hra, float* __restrict__ hrb,
                      float* __restrict__ hrc) {
    int z = blockIdx.y;
    const float* w1 = z == 0 ? w1a : (z == 1 ? w1b : w1c);
    const float* b1 = z == 0 ? b1a : (z == 1 ? b1b : b1c);
    float* hr = z == 0 ? hra : (z == 1 ? hrb : hrc);
    int idx = blockIdx.x * 256 + threadIdx.x;          // t*32 + j
    if (idx >= T_ * DH_) return;
    int t = idx / DH_, j = idx % DH_;
    float acc = b1[j];
    const float* cx = c_x + t * DM_;
    #pragma unroll
    for (int d = 0; d < DM_; ++d) acc += cx[d] * w1[d * DH_ + j];
    hr[idx] = fmaxf(acc, 0.f);
}

// ---------- fused meta+mhlin GEMM via bf16 MFMA ----------
// qkv[t,m] = sum_k Z[t,k]*W2p[k,m]; K=2112 (66 chunks of 32); tile 32x32, 2 waves.
// A-frag: m=lane&15, k=quad*8+j ; D: col=lane&15, row=quad*4+reg [learn_hip m89/m91]
__global__ __launch_bounds__(128) void k_meta_mfma(
    const float* __restrict__ hrA, const float* __restrict__ hrB,
    const float* __restrict__ xin,
    const float* __restrict__ w2A, const float* __restrict__ b2A,
    const float* __restrict__ w2B, const float* __restrict__ b2B,
    float* __restrict__ outA, float* __restrict__ outB) {
    const int bz = blockIdx.z;
    const float* hr = bz ? hrB : hrA;
    const float* w2 = bz ? w2B : w2A;
    const float* b2 = bz ? b2B : b2A;
    float* out = bz ? outB : outA;

    const int t0 = blockIdx.x * 32;
    const int m0 = blockIdx.y * 32;
    const int tid = threadIdx.x;

    __shared__ unsigned short Zs[32][40];
    __shared__ unsigned short Ws[32][40];

    const int wv = tid >> 6;
    const int lane = tid & 63;
    const int l15 = lane & 15;
    const int quad = lane >> 4;

    const int row = tid >> 2;
    const int q2 = (tid & 3) * 2;

    const int tA = t0 + row;
    const bool tok = (tA < T_);

    float4v acc0 = {0.f, 0.f, 0.f, 0.f};
    float4v acc1 = {0.f, 0.f, 0.f, 0.f};

    for (int kc = 0; kc < 66; ++kc) {
        const int j = kc >> 1;
        const int d0 = (kc & 1) * 32;
        const float* wrow = (j < DH_) ? (w2 + j * 12288) : b2;

        __syncthreads();
        {
            float f = 0.f;
            if (tok) f = (j < DH_) ? hr[tA * DH_ + j] : 1.f;
            const float* xp = xin + (tok ? tA : 0) * DM_ + d0;
            #pragma unroll
            for (int e = 0; e < 2; ++e) {
                int qq = q2 + e;
                float4v xv = *(const float4v*)(xp + qq * 4);
                short4v z;
                z.x = (short)f2bf(f * xv.x);
                z.y = (short)f2bf(f * xv.y);
                z.z = (short)f2bf(f * xv.z);
                z.w = (short)f2bf(f * xv.w);
                *(short4v*)&Zs[row][qq * 4] = z;
            }
        }
        {
            const float* wp = wrow + (m0 + row) * 64 + d0;
            #pragma unroll
            for (int e = 0; e < 2; ++e) {
                int qq = q2 + e;
                float4v wvv = *(const float4v*)(wp + qq * 4);
                short4v z;
                z.x = (short)f2bf(wvv.x);
                z.y = (short)f2bf(wvv.y);
                z.z = (short)f2bf(wvv.z);
                z.w = (short)f2bf(wvv.w);
                *(short4v*)&Ws[row][qq * 4] = z;
            }
        }
        __syncthreads();

        short8v a  = *(const short8v*)&Zs[wv * 16 + l15][quad * 8];
        short8v b0 = *(const short8v*)&Ws[l15][quad * 8];
        short8v b1 = *(const short8v*)&Ws[16 + l15][quad * 8];
        acc0 = __builtin_amdgcn_mfma_f32_16x16x32_bf16(a, b0, acc0, 0, 0, 0);
        acc1 = __builtin_amdgcn_mfma_f32_16x16x32_bf16(a, b1, acc1, 0, 0, 0);
    }

    const int col = m0 + l15;
    #pragma unroll
    for (int r = 0; r < 4; ++r) {
        int t = t0 + wv * 16 + quad * 4 + r;
        if (t < T_) {
            out[t * 192 + col] = acc0[r];
            out[t * 192 + col + 16] = acc1[r];
        }
    }
}

// ---------- retnet temporal retention: block per (b,n), 256 thr ----------
// LDS-staged QKV rows; lane = (h,k) computes output (q,h,k) for q = qq+{0,4,8}
__global__ __launch_bounds__(256) void k_retnet(const float* __restrict__ qkv,
                                                const float* __restrict__ Dm,
                                                float* __restrict__ att) {
    const int bn = blockIdx.x;           // b*N + n
    const int b = bn / N_, n = bn % N_;
    __shared__ float S[12][192];         // [p][g*64+h*8+k]
    __shared__ float Ds[8 * 145];        // D padded: [h*145 + q*12 + p]
    const int tid = threadIdx.x;
    for (int e = tid; e < 12 * 192; e += 256) {
        int p = e / 192, c = e % 192;
        S[p][c] = qkv[((size_t)((b * P_ + p) * N_ + n)) * 192 + c];
    }
    for (int e = tid; e < 1152; e += 256) {
        Ds[(e / 144) * 145 + (e % 144)] = Dm[e];
    }
    __syncthreads();
    const int qq = tid >> 6;             // 0..3
    const int lane = tid & 63;
    const int h = lane >> 3, k = lane & 7;
    for (int q = qq; q < P_; q += 4) {
        float Qv = S[q][h * 8 + k];
        float r[P_];
        float rsum = 0.f;
        #pragma unroll
        for (int p = 0; p < P_; ++p) {
            float prod = Qv * S[p][64 + h * 8 + k];
            prod += __shfl_xor(prod, 1, 64);
            prod += __shfl_xor(prod, 2, 64);
            prod += __shfl_xor(prod, 4, 64);
            float s = (prod / SQRT_DK) * Ds[h * 145 + q * 12 + p];
            r[p] = s; rsum += s;
        }
        float rs = fmaxf(fabsf(rsum), 1.0f);
        float acc = 0.f;
        #pragma unroll
        for (int p = 0; p < P_; ++p) acc += (r[p] / rs) * S[p][128 + h * 8 + k];
        att[((size_t)((b * P_ + q) * N_ + n)) * 64 + lane] = acc;
    }
}

// ---------- temporal enc-dec attention: same structure, softmax over p ----------
__global__ __launch_bounds__(256) void k_temporal(const float* __restrict__ qkv,
                                                  float* __restrict__ att) {
    const int bn = blockIdx.x;
    const int b = bn / N_, n = bn % N_;
    __shared__ float S[12][192];
    const int tid = threadIdx.x;
    for (int e = tid; e < 12 * 192; e += 256) {
        int p = e / 192, c = e % 192;
        S[p][c] = qkv[((size_t)((b * P_ + p) * N_ + n)) * 192 + c];
    }
    __syncthreads();
    const int qq = tid >> 6;
    const int lane = tid & 63;
    const int h = lane >> 3, k = lane & 7;
    for (int q = qq; q < P_; q += 4) {
        float Qv = S[q][h * 8 + k];
        float s[P_];
        float mx = -1e30f;
        #pragma unroll
        for (int p = 0; p < P_; ++p) {
            float prod = Qv * S[p][64 + h * 8 + k];
            prod += __shfl_xor(prod, 1, 64);
            prod += __shfl_xor(prod, 2, 64);
            prod += __shfl_xor(prod, 4, 64);
            float v = prod / SQRT_DK;
            s[p] = v; mx = fmaxf(mx, v);
        }
        float den = 0.f, acc = 0.f;
        #pragma unroll
        for (int p = 0; p < P_; ++p) {
            float e = expf(s[p] - mx);
            den += e;
            acc += e * S[p][128 + h * 8 + k];
        }
        att[((size_t)((b * P_ + q) * N_ + n)) * 64 + lane] = acc / den;
    }
}

// ---------- spatial attention v2: one wave per (token, graph) ----------
// block (ti, graph); lane=(h,k). nozero-softmax semantics preserved.
__global__ __launch_bounds__(64) void k_spatial2(
    const float* __restrict__ qkvA, const float* __restrict__ qkvB,
    const float* __restrict__ Tm, const float* __restrict__ Am,
    float* __restrict__ attA, float* __restrict__ attB) {
    const int ti = blockIdx.x;
    const int gsel = blockIdx.y;
    const float* qkv = gsel ? qkvB : qkvA;
    float* att = gsel ? attB : attA;
    const int i = ti % N_;
    const int bp = ti / N_;

    __shared__ float sT[N_ + 2];
    __shared__ float sS[8][177];

    const int lane = threadIdx.x;
    const int h = lane >> 3, k = lane & 7;
    (void)k;

    const float* Trow = gsel ? (Am + (size_t)ti * N_) : (Tm + (size_t)i * N_);
    for (int j = lane; j < N_; j += 64) sT[j] = Trow[j];
    __syncthreads();

    const float Qv = qkv[(size_t)ti * 192 + lane];
    const float* kbase = qkv + (size_t)bp * N_ * 192 + 64;

    // pass 1: scores -> LDS, row max (masked entries contribute 0)
    float mx = -1e30f;
    for (int j = 0; j < N_; ++j) {
        float prod = Qv * kbase[j * 192 + lane];
        prod += __shfl_xor(prod, 1, 64);
        prod += __shfl_xor(prod, 2, 64);
        prod += __shfl_xor(prod, 4, 64);
        float tv = sT[j];
        float s = (tv != 0.f) ? (prod / SQRT_DK) : 0.f;
        mx = fmaxf(mx, s);
        if ((lane & 7) == 0) sS[h][j] = s;
    }
    __syncthreads();

    // pass 2: e = exp(s-mx)*(s!=0); acc = sum e*T_ij*V ; out = acc/(den+1e-5)
    const float* vbase = qkv + (size_t)bp * N_ * 192 + 128;
    float den = 0.f, acc = 0.f;
    for (int j = 0; j < N_; ++j) {
        float s = sS[h][j];
        float e = (s != 0.f) ? expf(s - mx) : 0.f;
        den += e;
        acc += e * sT[j] * vbase[j * 192 + lane];
    }
    att[(size_t)ti * 64 + lane] = acc / (den + 1e-5f);
}

// ---------- gdc over G=8,C=8 for one output dim ----------
__device__ __forceinline__ float gdc8(const float* dv, const float* W1,
                                      const float* W2, int dm) {
    float a[8], s[8];
    #pragma unroll
    for (int g = 0; g < 8; ++g) {
        float aa = 0.f, ss = 0.f;
        #pragma unroll
        for (int c = 0; c < 8; ++c) {
            float d = dv[g * 8 + c];
            aa += d * W1[(g * 8 + c) * 64 + dm];
            ss += d * W2[(g * 8 + c) * 64 + dm];
        }
        a[g] = aa; s[g] = fmaxf(ss, 0.f);
    }
    float mx = s[0];
    #pragma unroll
    for (int g = 1; g < 8; ++g) mx = fmaxf(mx, s[g]);
    float den = 0.f, o = 0.f;
    #pragma unroll
    for (int g = 0; g < 8; ++g) { float e = expf(s[g] - mx); den += e; o += a[g] * e; }
    return o / den;
}

__device__ __forceinline__ float ln_out(float r, int dm, const float* g, const float* b) {
    float m = r, m2 = r * r;
    #pragma unroll
    for (int off = 32; off; off >>= 1) { m += __shfl_xor(m, off, 64); m2 += __shfl_xor(m2, off, 64); }
    m *= (1.f / 64.f); m2 *= (1.f / 64.f);
    float var = m2 - m * m;
    return (r - m) * rsqrtf(var + 1e-5f) * g[dm] + b[dm];
}

// ---------- fused gdc(H=8) + swish-gate + residual + LN ----------
__global__ __launch_bounds__(64) void k_gsl(const float* __restrict__ att, const float* __restrict__ xin,
    const float* W1, const float* W2,
    const float* wg, const float* bg,
    const float* wo, const float* bo,
    const float* lng, const float* lnb, float* __restrict__ xout) {
    int t = blockIdx.x, dm = threadIdx.x;
    __shared__ float dv[64], xv[64], swv[64];
    dv[dm] = att[t * 64 + dm];
    xv[dm] = xin[t * 64 + dm];
    __syncthreads();
    float o = gdc8(dv, W1, W2, dm);
    float hg = bg[dm];
    #pragma unroll
    for (int d = 0; d < 64; ++d) hg += xv[d] * wg[d * 64 + dm];
    hg *= o;
    swv[dm] = hg / (1.f + expf(-hg));
    __syncthreads();
    float ov = bo[dm];
    #pragma unroll
    for (int d = 0; d < 64; ++d) ov += swv[d] * wo[d * 64 + dm];
    float r = ov + xv[dm];
    xout[t * 64 + dm] = ln_out(r, dm, lng, lnb);
}

// ---------- spatial stage tail: gdc0 + gdc1 + g2(G=2,C=64) + swish + LN ----------
__global__ __launch_bounds__(64) void k_spatial_fuse(
    const float* __restrict__ att0, const float* __restrict__ att1, const float* __restrict__ x1,
    const float* gs0_W1, const float* gs0_W2,
    const float* gs1_W1, const float* gs1_W2,
    const float* g2_W1, const float* g2_W2,
    const float* wg, const float* bg,
    const float* wo, const float* bo,
    const float* lng, const float* lnb, float* __restrict__ xout) {
    int t = blockIdx.x, dm = threadIdx.x;
    __shared__ float d0[64], d1[64], o0s[64], o1s[64], xv[64], swv[64];
    d0[dm] = att0[t * 64 + dm];
    d1[dm] = att1[t * 64 + dm];
    xv[dm] = x1[t * 64 + dm];
    __syncthreads();
    o0s[dm] = gdc8(d0, gs0_W1, gs0_W2, dm);
    o1s[dm] = gdc8(d1, gs1_W1, gs1_W2, dm);
    __syncthreads();
    float a0 = 0.f, s0 = 0.f, a1 = 0.f, s1 = 0.f;
    #pragma unroll
    for (int c = 0; c < 64; ++c) {
        a0 += o0s[c] * g2_W1[c * 64 + dm];
        s0 += o0s[c] * g2_W2[c * 64 + dm];
        a1 += o1s[c] * g2_W1[(64 + c) * 64 + dm];
        s1 += o1s[c] * g2_W2[(64 + c) * 64 + dm];
    }
    s0 = fmaxf(s0, 0.f); s1 = fmaxf(s1, 0.f);
    float mx = fmaxf(s0, s1);
    float e0 = expf(s0 - mx), e1 = expf(s1 - mx);
    float o = (a0 * e0 + a1 * e1) / (e0 + e1);
    float hg = bg[dm];
    #pragma unroll
    for (int d = 0; d < 64; ++d) hg += xv[d] * wg[d * 64 + dm];
    hg *= o;
    swv[dm] = hg / (1.f + expf(-hg));
    __syncthreads();
    float ov = bo[dm];
    #pragma unroll
    for (int d = 0; d < 64; ++d) ov += swv[d] * wo[d * 64 + dm];
    float r = ov + xv[dm];
    xout[t * 64 + dm] = ln_out(r, dm, lng, lnb);
}

// ---------- q/k/v projections for enc-dec stage ----------
__global__ __launch_bounds__(64) void k_qkvproj(const float* __restrict__ x2,
    const float* __restrict__ enc,
    const float* wq, const float* wk, const float* wv,
    float* __restrict__ qkv) {
    int t = blockIdx.x, dm = threadIdx.x;
    __shared__ float xv[64], ev[64];
    xv[dm] = x2[t * 64 + dm];
    ev[dm] = enc[t * 64 + dm];
    __syncthreads();
    float aq = 0.f, ak = 0.f, av = 0.f;
    #pragma unroll
    for (int d = 0; d < 64; ++d) {
        aq += xv[d] * wq[d * 64 + dm];
        ak += ev[d] * wk[d * 64 + dm];
        av += ev[d] * wv[d * 64 + dm];
    }
    qkv[t * 192 + dm] = aq;
    qkv[t * 192 + 64 + dm] = ak;
    qkv[t * 192 + 128 + dm] = av;
}

// ---------- FFN + residual + LN -> fp32 output ----------
__global__ __launch_bounds__(64) void k_ffn(const float* __restrict__ x3,
    const float* w1, const float* b1,
    const float* w2, const float* b2,
    const float* lng, const float* lnb,
    float* __restrict__ out) {
    int t = blockIdx.x, dm = threadIdx.x;
    __shared__ float xv[64], hv[256];
    xv[dm] = x3[t * 64 + dm];
    __syncthreads();
    #pragma unroll
    for (int e = 0; e < 4; ++e) {
        int j = e * 64 + dm;
        float a = b1[j];
        #pragma unroll
        for (int d = 0; d < 64; ++d) a += xv[d] * w1[d * 256 + j];
        hv[j] = fmaxf(a, 0.f);
    }
    __syncthreads();
    float a = b2[dm];
    for (int j = 0; j < 256; ++j) a += hv[j] * w2[j * 64 + dm];
    float r = a + xv[dm];
    out[t * 64 + dm] = ln_out(r, dm, lng, lnb);
}

} // namespace

extern "C" void kernel_launch(void* const* d_in, const int* in_sizes, int n_in,
                              void* d_out, int out_size, void* d_ws, size_t ws_size,
                              hipStream_t stream) {
    (void)in_sizes; (void)n_in; (void)out_size; (void)ws_size;
    const float* x    = (const float*)d_in[0];
    const float* c_x  = (const float*)d_in[1];
    const float* enc  = (const float*)d_in[2];
    const float* Tm   = (const float*)d_in[3];
    const float* Am   = (const float*)d_in[4];
    const float* Dm   = (const float*)d_in[5];
    const float* mr_w1 = (const float*)d_in[6];
    const float* mr_b1 = (const float*)d_in[7];
    const float* mr_w2 = (const float*)d_in[8];
    const float* mr_b2 = (const float*)d_in[9];
    const float* ms0_w1 = (const float*)d_in[10];
    const float* ms0_b1 = (const float*)d_in[11];
    const float* ms0_w2 = (const float*)d_in[12];
    const float* ms0_b2 = (const float*)d_in[13];
    const float* ms1_w1 = (const float*)d_in[14];
    const float* ms1_b1 = (const float*)d_in[15];
    const float* ms1_w2 = (const float*)d_in[16];
    const float* ms1_b2 = (const float*)d_in[17];
    const float* gr_W1 = (const float*)d_in[18];
    const float* gr_W2 = (const float*)d_in[19];
    const float* gs0_W1 = (const float*)d_in[20];
    const float* gs0_W2 = (const float*)d_in[21];
    const float* gs1_W1 = (const float*)d_in[22];
    const float* gs1_W2 = (const float*)d_in[23];
    const float* g2_W1 = (const float*)d_in[24];
    const float* g2_W2 = (const float*)d_in[25];
    const float* ge_W1 = (const float*)d_in[26];
    const float* ge_W2 = (const float*)d_in[27];
    const float* swr_wg = (const float*)d_in[28];
    const float* swr_bg = (const float*)d_in[29];
    const float* swr_wo = (const float*)d_in[30];
    const float* swr_bo = (const float*)d_in[31];
    const float* sws_wg = (const float*)d_in[32];
    const float* sws_bg = (const float*)d_in[33];
    const float* sws_wo = (const float*)d_in[34];
    const float* sws_bo = (const float*)d_in[35];
    const float* swe_wg = (const float*)d_in[36];
    const float* swe_bg = (const float*)d_in[37];
    const float* swe_wo = (const float*)d_in[38];
    const float* swe_bo = (const float*)d_in[39];
    const float* lnr_g = (const float*)d_in[40];
    const float* lnr_b = (const float*)d_in[41];
    const float* lns_g = (const float*)d_in[42];
    const float* lns_b = (const float*)d_in[43];
    const float* lne_g = (const float*)d_in[44];
    const float* lne_b = (const float*)d_in[45];
    const float* lnf_g = (const float*)d_in[46];
    const float* lnf_b = (const float*)d_in[47];
    const float* wq = (const float*)d_in[48];
    const float* wk = (const float*)d_in[49];
    const float* wv = (const float*)d_in[50];
    const float* f_w1 = (const float*)d_in[51];
    const float* f_b1 = (const float*)d_in[52];
    const float* f_w2 = (const float*)d_in[53];
    const float* f_b2 = (const float*)d_in[54];

    // workspace layout (fp32), ~12.5 MB
    float* ws   = (float*)d_ws;
    float* hr   = ws;                 // 130560  (stage-2 graph0 hr)
    float* hr2  = hr   + T_ * DH_;    // 130560  (stage-2 graph1 hr)
    float* qkva = hr2  + T_ * DH_;    // 783360
    float* qkvb = qkva + T_ * 192;    // 783360
    float* atta = qkvb + T_ * 192;    // 261120
    float* attb = atta + T_ * DM_;    // 261120  (also reused as stage-1 hr buffer)
    float* x1f  = attb + T_ * DM_;    // 261120
    float* x2f  = x1f  + T_ * DM_;    // 261120
    float* x3f  = x2f  + T_ * DM_;    // 261120
    float* hr_r = attb;               // stage-1 hr lives in attb (consumed before
                                      // k_spatial2 writes attb)

    dim3 g1(128, 6, 1), g2g(128, 6, 2);

    // all three meta-hiddens depend only on c_x — one batched launch
    k_hr3<<<dim3(510, 3), 256, 0, stream>>>(c_x, mr_w1, mr_b1, ms0_w1, ms0_b1,
                                            ms1_w1, ms1_b1, hr_r, hr, hr2);

    // ---- stage 1: retnet retention ----
    k_meta_mfma<<<g1, 128, 0, stream>>>(hr_r, hr_r, x, mr_w2, mr_b2, mr_w2, mr_b2, qkva, qkva);
    k_retnet<<<B_ * N_, 256, 0, stream>>>(qkva, Dm, atta);
    k_gsl<<<T_, 64, 0, stream>>>(atta, x, gr_W1, gr_W2, swr_wg, swr_bg, swr_wo, swr_bo,
                                 lnr_g, lnr_b, x1f);

    // ---- stage 2: spatial (predefined T + adaptive A) ----
    k_meta_mfma<<<g2g, 128, 0, stream>>>(hr, hr2, x1f, ms0_w2, ms0_b2, ms1_w2, ms1_b2,
                                         qkva, qkvb);
    k_spatial2<<<dim3(T_, 2), 64, 0, stream>>>(qkva, qkvb, Tm, Am, atta, attb);
    k_spatial_fuse<<<T_, 64, 0, stream>>>(atta, attb, x1f, gs0_W1, gs0_W2, gs1_W1, gs1_W2,
                                          g2_W1, g2_W2, sws_wg, sws_bg, sws_wo, sws_bo,
                                          lns_g, lns_b, x2f);

    // ---- stage 3: temporal encoder-decoder attention ----
    k_qkvproj<<<T_, 64, 0, stream>>>(x2f, enc, wq, wk, wv, qkva);
    k_temporal<<<B_ * N_, 256, 0, stream>>>(qkva, atta);
    k_gsl<<<T_, 64, 0, stream>>>(atta, x2f, ge_W1, ge_W2, swe_wg, swe_bg, swe_wo, swe_bo,
                                 lne_g, lne_b, x3f);

    // ---- stage 4: FFN ----
    k_ffn<<<T_, 64, 0, stream>>>(x3f, f_w1, f_b1, f_w2, f_b2, lnf_g, lnf_b, (float*)d_out);
}

// Round 5
// 436.866 us; speedup vs baseline: 2.5327x; 1.1650x over previous
//
#include <hip/hip_runtime.h>
#include <hip/hip_bf16.h>
#include <math.h>

namespace {

constexpr int B_ = 2, P_ = 12, N_ = 170, DM_ = 64, H_ = 8, DK_ = 8, DH_ = 32, DF_ = 256;
constexpr int T_ = B_ * P_ * N_;        // 4080 tokens
constexpr float SQRT_DK = 2.8284271247461903f;

typedef __attribute__((ext_vector_type(4))) short short4v;
typedef __attribute__((ext_vector_type(8))) short short8v;
typedef __attribute__((ext_vector_type(4))) float float4v;

// float -> bf16 bits, round-to-nearest-even
__device__ __forceinline__ unsigned short f2bf(float x) {
    union { float f; unsigned int u; } c; c.f = x;
    unsigned int r = (c.u + 0x7FFFu + ((c.u >> 16) & 1u)) >> 16;
    return (unsigned short)r;
}

// ---------- meta hidden (x3 batched): hr = relu(c_x @ w1 + b1)  [T_,32] ----------
__global__ void k_hr3(const float* __restrict__ c_x,
                      const float* __restrict__ w1a, const float* __restrict__ b1a,
                      const float* __restrict__ w1b, const float* __restrict__ b1b,
                      const float* __restrict__ w1c, const float* __restrict__ b1c,
                      float* __restrict__ hra, float* __restrict__ hrb,
                      float* __restrict__ hrc) {
    int z = blockIdx.y;
    const float* w1 = z == 0 ? w1a : (z == 1 ? w1b : w1c);
    const float* b1 = z == 0 ? b1a : (z == 1 ? b1b : b1c);
    float* hr = z == 0 ? hra : (z == 1 ? hrb : hrc);
    int idx = blockIdx.x * 256 + threadIdx.x;          // t*32 + j
    if (idx >= T_ * DH_) return;
    int t = idx / DH_, j = idx % DH_;
    float acc = b1[j];
    const float* cx = c_x + t * DM_;
    #pragma unroll
    for (int d = 0; d < DM_; ++d) acc += cx[d] * w1[d * DH_ + j];
    hr[idx] = fmaxf(acc, 0.f);
}

// ---------- fused meta+mhlin GEMM via bf16 MFMA ----------
// qkv[t,m] = sum_k Z[t,k]*W2p[k,m]; K=2112 (66 chunks of 32); tile 32x32, 2 waves.
__global__ __launch_bounds__(128) void k_meta_mfma(
    const float* __restrict__ hrA, const float* __restrict__ hrB,
    const float* __restrict__ xin,
    const float* __restrict__ w2A, const float* __restrict__ b2A,
    const float* __restrict__ w2B, const float* __restrict__ b2B,
    float* __restrict__ outA, float* __restrict__ outB) {
    const int bz = blockIdx.z;
    const float* hr = bz ? hrB : hrA;
    const float* w2 = bz ? w2B : w2A;
    const float* b2 = bz ? b2B : b2A;
    float* out = bz ? outB : outA;

    const int t0 = blockIdx.x * 32;
    const int m0 = blockIdx.y * 32;
    const int tid = threadIdx.x;

    __shared__ unsigned short Zs[32][40];
    __shared__ unsigned short Ws[32][40];

    const int wv = tid >> 6;
    const int lane = tid & 63;
    const int l15 = lane & 15;
    const int quad = lane >> 4;

    const int row = tid >> 2;
    const int q2 = (tid & 3) * 2;

    const int tA = t0 + row;
    const bool tok = (tA < T_);

    float4v acc0 = {0.f, 0.f, 0.f, 0.f};
    float4v acc1 = {0.f, 0.f, 0.f, 0.f};

    for (int kc = 0; kc < 66; ++kc) {
        const int j = kc >> 1;
        const int d0 = (kc & 1) * 32;
        const float* wrow = (j < DH_) ? (w2 + j * 12288) : b2;

        __syncthreads();
        {
            float f = 0.f;
            if (tok) f = (j < DH_) ? hr[tA * DH_ + j] : 1.f;
            const float* xp = xin + (tok ? tA : 0) * DM_ + d0;
            #pragma unroll
            for (int e = 0; e < 2; ++e) {
                int qq = q2 + e;
                float4v xv = *(const float4v*)(xp + qq * 4);
                short4v z;
                z.x = (short)f2bf(f * xv.x);
                z.y = (short)f2bf(f * xv.y);
                z.z = (short)f2bf(f * xv.z);
                z.w = (short)f2bf(f * xv.w);
                *(short4v*)&Zs[row][qq * 4] = z;
            }
        }
        {
            const float* wp = wrow + (m0 + row) * 64 + d0;
            #pragma unroll
            for (int e = 0; e < 2; ++e) {
                int qq = q2 + e;
                float4v wvv = *(const float4v*)(wp + qq * 4);
                short4v z;
                z.x = (short)f2bf(wvv.x);
                z.y = (short)f2bf(wvv.y);
                z.z = (short)f2bf(wvv.z);
                z.w = (short)f2bf(wvv.w);
                *(short4v*)&Ws[row][qq * 4] = z;
            }
        }
        __syncthreads();

        short8v a  = *(const short8v*)&Zs[wv * 16 + l15][quad * 8];
        short8v b0 = *(const short8v*)&Ws[l15][quad * 8];
        short8v b1 = *(const short8v*)&Ws[16 + l15][quad * 8];
        acc0 = __builtin_amdgcn_mfma_f32_16x16x32_bf16(a, b0, acc0, 0, 0, 0);
        acc1 = __builtin_amdgcn_mfma_f32_16x16x32_bf16(a, b1, acc1, 0, 0, 0);
    }

    const int col = m0 + l15;
    #pragma unroll
    for (int r = 0; r < 4; ++r) {
        int t = t0 + wv * 16 + quad * 4 + r;
        if (t < T_) {
            out[t * 192 + col] = acc0[r];
            out[t * 192 + col + 16] = acc1[r];
        }
    }
}

// ---------- retnet temporal retention: block per (b,n), 256 thr ----------
__global__ __launch_bounds__(256) void k_retnet(const float* __restrict__ qkv,
                                                const float* __restrict__ Dm,
                                                float* __restrict__ att) {
    const int bn = blockIdx.x;           // b*N + n
    const int b = bn / N_, n = bn % N_;
    __shared__ float S[12][192];
    __shared__ float Ds[8 * 145];
    const int tid = threadIdx.x;
    for (int e = tid; e < 12 * 192; e += 256) {
        int p = e / 192, c = e % 192;
        S[p][c] = qkv[((size_t)((b * P_ + p) * N_ + n)) * 192 + c];
    }
    for (int e = tid; e < 1152; e += 256) {
        Ds[(e / 144) * 145 + (e % 144)] = Dm[e];
    }
    __syncthreads();
    const int qq = tid >> 6;
    const int lane = tid & 63;
    const int h = lane >> 3, k = lane & 7;
    for (int q = qq; q < P_; q += 4) {
        float Qv = S[q][h * 8 + k];
        float r[P_];
        float rsum = 0.f;
        #pragma unroll
        for (int p = 0; p < P_; ++p) {
            float prod = Qv * S[p][64 + h * 8 + k];
            prod += __shfl_xor(prod, 1, 64);
            prod += __shfl_xor(prod, 2, 64);
            prod += __shfl_xor(prod, 4, 64);
            float s = (prod / SQRT_DK) * Ds[h * 145 + q * 12 + p];
            r[p] = s; rsum += s;
        }
        float rs = fmaxf(fabsf(rsum), 1.0f);
        float acc = 0.f;
        #pragma unroll
        for (int p = 0; p < P_; ++p) acc += (r[p] / rs) * S[p][128 + h * 8 + k];
        att[((size_t)((b * P_ + q) * N_ + n)) * 64 + lane] = acc;
    }
}

// ---------- temporal enc-dec attention ----------
__global__ __launch_bounds__(256) void k_temporal(const float* __restrict__ qkv,
                                                  float* __restrict__ att) {
    const int bn = blockIdx.x;
    const int b = bn / N_, n = bn % N_;
    __shared__ float S[12][192];
    const int tid = threadIdx.x;
    for (int e = tid; e < 12 * 192; e += 256) {
        int p = e / 192, c = e % 192;
        S[p][c] = qkv[((size_t)((b * P_ + p) * N_ + n)) * 192 + c];
    }
    __syncthreads();
    const int qq = tid >> 6;
    const int lane = tid & 63;
    const int h = lane >> 3, k = lane & 7;
    for (int q = qq; q < P_; q += 4) {
        float Qv = S[q][h * 8 + k];
        float s[P_];
        float mx = -1e30f;
        #pragma unroll
        for (int p = 0; p < P_; ++p) {
            float prod = Qv * S[p][64 + h * 8 + k];
            prod += __shfl_xor(prod, 1, 64);
            prod += __shfl_xor(prod, 2, 64);
            prod += __shfl_xor(prod, 4, 64);
            float v = prod / SQRT_DK;
            s[p] = v; mx = fmaxf(mx, v);
        }
        float den = 0.f, acc = 0.f;
        #pragma unroll
        for (int p = 0; p < P_; ++p) {
            float e = expf(s[p] - mx);
            den += e;
            acc += e * S[p][128 + h * 8 + k];
        }
        att[((size_t)((b * P_ + q) * N_ + n)) * 64 + lane] = acc / den;
    }
}

// ---------- spatial attention v3: block (bp, h, graph); lanes span j ----------
// Per row i: coalesced T loads, per-lane 8-dot from LDS, ONE max-reduce and ONE
// den-reduce per row (12 shuffles total), P-row via per-wave LDS, PV as 8x8
// lane grid + 3 shuffles. nozero-softmax semantics preserved.
__global__ __launch_bounds__(256) void k_spatial3(
    const float* __restrict__ qkvA, const float* __restrict__ qkvB,
    const float* __restrict__ Tm, const float* __restrict__ Am,
    float* __restrict__ attA, float* __restrict__ attB) {
    const int bp = blockIdx.x;          // 0..23
    const int h = blockIdx.y;           // 0..7
    const int g = blockIdx.z;           // 0,1
    const float* qkv = g ? qkvB : qkvA;
    float* att = g ? attB : attA;

    __shared__ float sQ[192][8], sK[192][8], sV[192][8];
    __shared__ float sW[4][192];

    const int tid = threadIdx.x;
    // stage Q/K/V slice for (bp,h); rows >= N_ zeroed (PV loop runs to 192)
    for (int e = tid; e < 192 * 2; e += 256) {
        int j = e >> 1, kk = (e & 1) * 4;
        float4v q = {0.f, 0.f, 0.f, 0.f}, k4 = q, v4 = q;
        if (j < N_) {
            const float* row = qkv + (size_t)(bp * N_ + j) * 192 + h * 8 + kk;
            q  = *(const float4v*)(row);
            k4 = *(const float4v*)(row + 64);
            v4 = *(const float4v*)(row + 128);
        }
        *(float4v*)&sQ[j][kk] = q;
        *(float4v*)&sK[j][kk] = k4;
        *(float4v*)&sV[j][kk] = v4;
    }
    __syncthreads();

    const int wv = tid >> 6;
    const int lane = tid & 63;
    const int j8 = lane >> 3, kk = lane & 7;

    for (int i = wv; i < N_; i += 4) {
        const float* Trow = g ? (Am + (size_t)(bp * N_ + i) * N_) : (Tm + (size_t)i * N_);
        float4v qa = *(const float4v*)&sQ[i][0];   // same addr all lanes: broadcast
        float4v qb = *(const float4v*)&sQ[i][4];
        float Qi[8] = {qa.x, qa.y, qa.z, qa.w, qb.x, qb.y, qb.z, qb.w};

        float sloc[3], tloc[3];
        float mx = -1e30f;
        #pragma unroll
        for (int c = 0; c < 3; ++c) {
            int j = c * 64 + lane;
            float tv = 0.f, s = -1e30f;
            if (j < N_) {
                tv = Trow[j];
                if (tv != 0.f) {
                    float dot = 0.f;
                    #pragma unroll
                    for (int k = 0; k < 8; ++k) dot += Qi[k] * sK[j][k];
                    s = dot / SQRT_DK;
                } else {
                    s = 0.f;   // masked entries are exact zeros and DO enter the max
                }
            }
            sloc[c] = s; tloc[c] = tv;
            mx = fmaxf(mx, s);
        }
        #pragma unroll
        for (int off = 1; off < 64; off <<= 1) mx = fmaxf(mx, __shfl_xor(mx, off, 64));

        float den = 0.f;
        #pragma unroll
        for (int c = 0; c < 3; ++c) {
            float s = sloc[c];
            float e = (s != 0.f) ? expf(s - mx) : 0.f;  // j>=N_: s=-1e30 -> e==0
            den += e;
            sW[wv][c * 64 + lane] = e * tloc[c];
        }
        #pragma unroll
        for (int off = 1; off < 64; off <<= 1) den += __shfl_xor(den, off, 64);

        // PV: lane (j8,kk): partial over j = j8 mod 8 (sW rows >=N_ are 0; sV zeroed)
        float acc = 0.f;
        #pragma unroll 4
        for (int j = j8; j < 192; j += 8) acc += sW[wv][j] * sV[j][kk];
        acc += __shfl_xor(acc, 8, 64);
        acc += __shfl_xor(acc, 16, 64);
        acc += __shfl_xor(acc, 32, 64);
        if (lane < 8)
            att[(size_t)(bp * N_ + i) * 64 + h * 8 + lane] = acc / (den + 1e-5f);
    }
}

// ---------- gdc over G=8,C=8 for one output dim ----------
__device__ __forceinline__ float gdc8(const float* dv, const float* W1,
                                      const float* W2, int dm) {
    float a[8], s[8];
    #pragma unroll
    for (int g = 0; g < 8; ++g) {
        float aa = 0.f, ss = 0.f;
        #pragma unroll
        for (int c = 0; c < 8; ++c) {
            float d = dv[g * 8 + c];
            aa += d * W1[(g * 8 + c) * 64 + dm];
            ss += d * W2[(g * 8 + c) * 64 + dm];
        }
        a[g] = aa; s[g] = fmaxf(ss, 0.f);
    }
    float mx = s[0];
    #pragma unroll
    for (int g = 1; g < 8; ++g) mx = fmaxf(mx, s[g]);
    float den = 0.f, o = 0.f;
    #pragma unroll
    for (int g = 0; g < 8; ++g) { float e = expf(s[g] - mx); den += e; o += a[g] * e; }
    return o / den;
}

__device__ __forceinline__ float ln_out(float r, int dm, const float* g, const float* b) {
    float m = r, m2 = r * r;
    #pragma unroll
    for (int off = 32; off; off >>= 1) { m += __shfl_xor(m, off, 64); m2 += __shfl_xor(m2, off, 64); }
    m *= (1.f / 64.f); m2 *= (1.f / 64.f);
    float var = m2 - m * m;
    return (r - m) * rsqrtf(var + 1e-5f) * g[dm] + b[dm];
}

// ---------- fused gdc(H=8) + swish-gate + residual + LN ----------
__global__ __launch_bounds__(64) void k_gsl(const float* __restrict__ att, const float* __restrict__ xin,
    const float* W1, const float* W2,
    const float* wg, const float* bg,
    const float* wo, const float* bo,
    const float* lng, const float* lnb, float* __restrict__ xout) {
    int t = blockIdx.x, dm = threadIdx.x;
    __shared__ float dv[64], xv[64], swv[64];
    dv[dm] = att[t * 64 + dm];
    xv[dm] = xin[t * 64 + dm];
    __syncthreads();
    float o = gdc8(dv, W1, W2, dm);
    float hg = bg[dm];
    #pragma unroll
    for (int d = 0; d < 64; ++d) hg += xv[d] * wg[d * 64 + dm];
    hg *= o;
    swv[dm] = hg / (1.f + expf(-hg));
    __syncthreads();
    float ov = bo[dm];
    #pragma unroll
    for (int d = 0; d < 64; ++d) ov += swv[d] * wo[d * 64 + dm];
    float r = ov + xv[dm];
    xout[t * 64 + dm] = ln_out(r, dm, lng, lnb);
}

// ---------- spatial stage tail: gdc0 + gdc1 + g2(G=2,C=64) + swish + LN ----------
__global__ __launch_bounds__(64) void k_spatial_fuse(
    const float* __restrict__ att0, const float* __restrict__ att1, const float* __restrict__ x1,
    const float* gs0_W1, const float* gs0_W2,
    const float* gs1_W1, const float* gs1_W2,
    const float* g2_W1, const float* g2_W2,
    const float* wg, const float* bg,
    const float* wo, const float* bo,
    const float* lng, const float* lnb, float* __restrict__ xout) {
    int t = blockIdx.x, dm = threadIdx.x;
    __shared__ float d0[64], d1[64], o0s[64], o1s[64], xv[64], swv[64];
    d0[dm] = att0[t * 64 + dm];
    d1[dm] = att1[t * 64 + dm];
    xv[dm] = x1[t * 64 + dm];
    __syncthreads();
    o0s[dm] = gdc8(d0, gs0_W1, gs0_W2, dm);
    o1s[dm] = gdc8(d1, gs1_W1, gs1_W2, dm);
    __syncthreads();
    float a0 = 0.f, s0 = 0.f, a1 = 0.f, s1 = 0.f;
    #pragma unroll
    for (int c = 0; c < 64; ++c) {
        a0 += o0s[c] * g2_W1[c * 64 + dm];
        s0 += o0s[c] * g2_W2[c * 64 + dm];
        a1 += o1s[c] * g2_W1[(64 + c) * 64 + dm];
        s1 += o1s[c] * g2_W2[(64 + c) * 64 + dm];
    }
    s0 = fmaxf(s0, 0.f); s1 = fmaxf(s1, 0.f);
    float mx = fmaxf(s0, s1);
    float e0 = expf(s0 - mx), e1 = expf(s1 - mx);
    float o = (a0 * e0 + a1 * e1) / (e0 + e1);
    float hg = bg[dm];
    #pragma unroll
    for (int d = 0; d < 64; ++d) hg += xv[d] * wg[d * 64 + dm];
    hg *= o;
    swv[dm] = hg / (1.f + expf(-hg));
    __syncthreads();
    float ov = bo[dm];
    #pragma unroll
    for (int d = 0; d < 64; ++d) ov += swv[d] * wo[d * 64 + dm];
    float r = ov + xv[dm];
    xout[t * 64 + dm] = ln_out(r, dm, lng, lnb);
}

// ---------- q/k/v projections for enc-dec stage ----------
__global__ __launch_bounds__(64) void k_qkvproj(const float* __restrict__ x2,
    const float* __restrict__ enc,
    const float* wq, const float* wk, const float* wv,
    float* __restrict__ qkv) {
    int t = blockIdx.x, dm = threadIdx.x;
    __shared__ float xv[64], ev[64];
    xv[dm] = x2[t * 64 + dm];
    ev[dm] = enc[t * 64 + dm];
    __syncthreads();
    float aq = 0.f, ak = 0.f, av = 0.f;
    #pragma unroll
    for (int d = 0; d < 64; ++d) {
        aq += xv[d] * wq[d * 64 + dm];
        ak += ev[d] * wk[d * 64 + dm];
        av += ev[d] * wv[d * 64 + dm];
    }
    qkv[t * 192 + dm] = aq;
    qkv[t * 192 + 64 + dm] = ak;
    qkv[t * 192 + 128 + dm] = av;
}

// ---------- FFN + residual + LN -> fp32 output ----------
__global__ __launch_bounds__(64) void k_ffn(const float* __restrict__ x3,
    const float* w1, const float* b1,
    const float* w2, const float* b2,
    const float* lng, const float* lnb,
    float* __restrict__ out) {
    int t = blockIdx.x, dm = threadIdx.x;
    __shared__ float xv[64], hv[256];
    xv[dm] = x3[t * 64 + dm];
    __syncthreads();
    #pragma unroll
    for (int e = 0; e < 4; ++e) {
        int j = e * 64 + dm;
        float a = b1[j];
        #pragma unroll
        for (int d = 0; d < 64; ++d) a += xv[d] * w1[d * 256 + j];
        hv[j] = fmaxf(a, 0.f);
    }
    __syncthreads();
    float a = b2[dm];
    for (int j = 0; j < 256; ++j) a += hv[j] * w2[j * 64 + dm];
    float r = a + xv[dm];
    out[t * 64 + dm] = ln_out(r, dm, lng, lnb);
}

} // namespace

extern "C" void kernel_launch(void* const* d_in, const int* in_sizes, int n_in,
                              void* d_out, int out_size, void* d_ws, size_t ws_size,
                              hipStream_t stream) {
    (void)in_sizes; (void)n_in; (void)out_size; (void)ws_size;
    const float* x    = (const float*)d_in[0];
    const float* c_x  = (const float*)d_in[1];
    const float* enc  = (const float*)d_in[2];
    const float* Tm   = (const float*)d_in[3];
    const float* Am   = (const float*)d_in[4];
    const float* Dm   = (const float*)d_in[5];
    const float* mr_w1 = (const float*)d_in[6];
    const float* mr_b1 = (const float*)d_in[7];
    const float* mr_w2 = (const float*)d_in[8];
    const float* mr_b2 = (const float*)d_in[9];
    const float* ms0_w1 = (const float*)d_in[10];
    const float* ms0_b1 = (const float*)d_in[11];
    const float* ms0_w2 = (const float*)d_in[12];
    const float* ms0_b2 = (const float*)d_in[13];
    const float* ms1_w1 = (const float*)d_in[14];
    const float* ms1_b1 = (const float*)d_in[15];
    const float* ms1_w2 = (const float*)d_in[16];
    const float* ms1_b2 = (const float*)d_in[17];
    const float* gr_W1 = (const float*)d_in[18];
    const float* gr_W2 = (const float*)d_in[19];
    const float* gs0_W1 = (const float*)d_in[20];
    const float* gs0_W2 = (const float*)d_in[21];
    const float* gs1_W1 = (const float*)d_in[22];
    const float* gs1_W2 = (const float*)d_in[23];
    const float* g2_W1 = (const float*)d_in[24];
    const float* g2_W2 = (const float*)d_in[25];
    const float* ge_W1 = (const float*)d_in[26];
    const float* ge_W2 = (const float*)d_in[27];
    const float* swr_wg = (const float*)d_in[28];
    const float* swr_bg = (const float*)d_in[29];
    const float* swr_wo = (const float*)d_in[30];
    const float* swr_bo = (const float*)d_in[31];
    const float* sws_wg = (const float*)d_in[32];
    const float* sws_bg = (const float*)d_in[33];
    const float* sws_wo = (const float*)d_in[34];
    const float* sws_bo = (const float*)d_in[35];
    const float* swe_wg = (const float*)d_in[36];
    const float* swe_bg = (const float*)d_in[37];
    const float* swe_wo = (const float*)d_in[38];
    const float* swe_bo = (const float*)d_in[39];
    const float* lnr_g = (const float*)d_in[40];
    const float* lnr_b = (const float*)d_in[41];
    const float* lns_g = (const float*)d_in[42];
    const float* lns_b = (const float*)d_in[43];
    const float* lne_g = (const float*)d_in[44];
    const float* lne_b = (const float*)d_in[45];
    const float* lnf_g = (const float*)d_in[46];
    const float* lnf_b = (const float*)d_in[47];
    const float* wq = (const float*)d_in[48];
    const float* wk = (const float*)d_in[49];
    const float* wv = (const float*)d_in[50];
    const float* f_w1 = (const float*)d_in[51];
    const float* f_b1 = (const float*)d_in[52];
    const float* f_w2 = (const float*)d_in[53];
    const float* f_b2 = (const float*)d_in[54];

    // workspace layout (fp32), ~12.5 MB
    float* ws   = (float*)d_ws;
    float* hr   = ws;                 // stage-2 graph0 hr
    float* hr2  = hr   + T_ * DH_;    // stage-2 graph1 hr
    float* qkva = hr2  + T_ * DH_;
    float* qkvb = qkva + T_ * 192;
    float* atta = qkvb + T_ * 192;
    float* attb = atta + T_ * DM_;    // also reused as stage-1 hr buffer
    float* x1f  = attb + T_ * DM_;
    float* x2f  = x1f  + T_ * DM_;
    float* x3f  = x2f  + T_ * DM_;
    float* hr_r = attb;               // consumed before k_spatial3 writes attb

    dim3 g1(128, 6, 1), g2g(128, 6, 2);

    // all three meta-hiddens depend only on c_x — one batched launch
    k_hr3<<<dim3(510, 3), 256, 0, stream>>>(c_x, mr_w1, mr_b1, ms0_w1, ms0_b1,
                                            ms1_w1, ms1_b1, hr_r, hr, hr2);

    // ---- stage 1: retnet retention ----
    k_meta_mfma<<<g1, 128, 0, stream>>>(hr_r, hr_r, x, mr_w2, mr_b2, mr_w2, mr_b2, qkva, qkva);
    k_retnet<<<B_ * N_, 256, 0, stream>>>(qkva, Dm, atta);
    k_gsl<<<T_, 64, 0, stream>>>(atta, x, gr_W1, gr_W2, swr_wg, swr_bg, swr_wo, swr_bo,
                                 lnr_g, lnr_b, x1f);

    // ---- stage 2: spatial (predefined T + adaptive A) ----
    k_meta_mfma<<<g2g, 128, 0, stream>>>(hr, hr2, x1f, ms0_w2, ms0_b2, ms1_w2, ms1_b2,
                                         qkva, qkvb);
    k_spatial3<<<dim3(B_ * P_, H_, 2), 256, 0, stream>>>(qkva, qkvb, Tm, Am, atta, attb);
    k_spatial_fuse<<<T_, 64, 0, stream>>>(atta, attb, x1f, gs0_W1, gs0_W2, gs1_W1, gs1_W2,
                                          g2_W1, g2_W2, sws_wg, sws_bg, sws_wo, sws_bo,
                                          lns_g, lns_b, x2f);

    // ---- stage 3: temporal encoder-decoder attention ----
    k_qkvproj<<<T_, 64, 0, stream>>>(x2f, enc, wq, wk, wv, qkva);
    k_temporal<<<B_ * N_, 256, 0, stream>>>(qkva, atta);
    k_gsl<<<T_, 64, 0, stream>>>(atta, x2f, ge_W1, ge_W2, swe_wg, swe_bg, swe_wo, swe_bo,
                                 lne_g, lne_b, x3f);

    // ---- stage 4: FFN ----
    k_ffn<<<T_, 64, 0, stream>>>(x3f, f_w1, f_b1, f_w2, f_b2, lnf_g, lnf_b, (float*)d_out);
}

// Round 6
// 388.231 us; speedup vs baseline: 2.8500x; 1.1253x over previous
//
#include <hip/hip_runtime.h>
#include <hip/hip_bf16.h>
#include <math.h>

namespace {

constexpr int B_ = 2, P_ = 12, N_ = 170, DM_ = 64, H_ = 8, DK_ = 8, DH_ = 32, DF_ = 256;
constexpr int T_ = B_ * P_ * N_;        // 4080 tokens
constexpr float SQRT_DK = 2.8284271247461903f;

typedef __attribute__((ext_vector_type(4))) short short4v;
typedef __attribute__((ext_vector_type(8))) short short8v;
typedef __attribute__((ext_vector_type(4))) float float4v;

// float -> bf16 bits, round-to-nearest-even
__device__ __forceinline__ unsigned short f2bf(float x) {
    union { float f; unsigned int u; } c; c.f = x;
    unsigned int r = (c.u + 0x7FFFu + ((c.u >> 16) & 1u)) >> 16;
    return (unsigned short)r;
}

// ---------- meta hidden (x3 batched): hr = relu(c_x @ w1 + b1)  [T_,32] ----------
__global__ void k_hr3(const float* __restrict__ c_x,
                      const float* __restrict__ w1a, const float* __restrict__ b1a,
                      const float* __restrict__ w1b, const float* __restrict__ b1b,
                      const float* __restrict__ w1c, const float* __restrict__ b1c,
                      float* __restrict__ hra, float* __restrict__ hrb,
                      float* __restrict__ hrc) {
    int z = blockIdx.y;
    const float* w1 = z == 0 ? w1a : (z == 1 ? w1b : w1c);
    const float* b1 = z == 0 ? b1a : (z == 1 ? b1b : b1c);
    float* hr = z == 0 ? hra : (z == 1 ? hrb : hrc);
    int idx = blockIdx.x * 256 + threadIdx.x;          // t*32 + j
    if (idx >= T_ * DH_) return;
    int t = idx / DH_, j = idx % DH_;
    float acc = b1[j];
    const float* cx = c_x + t * DM_;
    #pragma unroll
    for (int d = 0; d < DM_; ++d) acc += cx[d] * w1[d * DH_ + j];
    hr[idx] = fmaxf(acc, 0.f);
}

// ---------- fused meta+mhlin GEMM via bf16 MFMA, fragment-order LDS ----------
// qkv[t,m] = sum_k Z[t,k]*W2p[k,m]; K=2112 (66 chunks of 32); tile 32x32, 2 waves.
// LDS holds A/B tiles directly in MFMA fragment order:
//   A[m=lane&15][k=(lane>>4)*8+j]  ->  Zf[wv][lane][j]
//   B[n=lane&15][k=(lane>>4)*8+j]  ->  Wf[n>>4][lane][j]
// Staging thread (row 0..31, qq 0..7 covering k=qq*4..+3) writes
//   frag[row>>4][(row&15)+16*(qq>>1)][(qq&1)*4 ..+3]  (<=2-way bank aliasing).
// Frag reads are lane-linear ds_read_b128 (canonical conflict-free layout).
__global__ __launch_bounds__(128) void k_meta_mfma(
    const float* __restrict__ hrA, const float* __restrict__ hrB,
    const float* __restrict__ xin,
    const float* __restrict__ w2A, const float* __restrict__ b2A,
    const float* __restrict__ w2B, const float* __restrict__ b2B,
    float* __restrict__ outA, float* __restrict__ outB) {
    const int bz = blockIdx.z;
    const float* hr = bz ? hrB : hrA;
    const float* w2 = bz ? w2B : w2A;
    const float* b2 = bz ? b2B : b2A;
    float* out = bz ? outB : outA;

    const int t0 = blockIdx.x * 32;
    const int m0 = blockIdx.y * 32;
    const int tid = threadIdx.x;

    __shared__ unsigned short Zf[2][64][8];   // A-frags per wave
    __shared__ unsigned short Wf[2][64][8];   // B-frags b0 (n 0-15), b1 (n 16-31)

    const int wv = tid >> 6;
    const int lane = tid & 63;
    const int l15 = lane & 15;
    const int quad = lane >> 4;

    const int row = tid >> 2;            // 0..31
    const int q2 = (tid & 3) * 2;        // qq = q2, q2+1

    const int tA = t0 + row;
    const bool tok = (tA < T_);

    float4v acc0 = {0.f, 0.f, 0.f, 0.f};
    float4v acc1 = {0.f, 0.f, 0.f, 0.f};

    for (int kc = 0; kc < 66; ++kc) {
        const int j = kc >> 1;
        const int d0 = (kc & 1) * 32;
        const float* wrow = (j < DH_) ? (w2 + j * 12288) : b2;

        __syncthreads();
        // stage A (Z tile)
        {
            float f = 0.f;
            if (tok) f = (j < DH_) ? hr[tA * DH_ + j] : 1.f;
            const float* xp = xin + (tok ? tA : 0) * DM_ + d0;
            #pragma unroll
            for (int e = 0; e < 2; ++e) {
                int qq = q2 + e;
                float4v xv = *(const float4v*)(xp + qq * 4);
                short4v z;
                z.x = (short)f2bf(f * xv.x);
                z.y = (short)f2bf(f * xv.y);
                z.z = (short)f2bf(f * xv.z);
                z.w = (short)f2bf(f * xv.w);
                *(short4v*)&Zf[row >> 4][(row & 15) + 16 * (qq >> 1)][(qq & 1) * 4] = z;
            }
        }
        // stage B (W tile)
        {
            const float* wp = wrow + (m0 + row) * 64 + d0;
            #pragma unroll
            for (int e = 0; e < 2; ++e) {
                int qq = q2 + e;
                float4v wvv = *(const float4v*)(wp + qq * 4);
                short4v z;
                z.x = (short)f2bf(wvv.x);
                z.y = (short)f2bf(wvv.y);
                z.z = (short)f2bf(wvv.z);
                z.w = (short)f2bf(wvv.w);
                *(short4v*)&Wf[row >> 4][(row & 15) + 16 * (qq >> 1)][(qq & 1) * 4] = z;
            }
        }
        __syncthreads();

        short8v a  = *(const short8v*)&Zf[wv][lane][0];
        short8v b0 = *(const short8v*)&Wf[0][lane][0];
        short8v b1 = *(const short8v*)&Wf[1][lane][0];
        acc0 = __builtin_amdgcn_mfma_f32_16x16x32_bf16(a, b0, acc0, 0, 0, 0);
        acc1 = __builtin_amdgcn_mfma_f32_16x16x32_bf16(a, b1, acc1, 0, 0, 0);
    }

    const int col = m0 + l15;
    #pragma unroll
    for (int r = 0; r < 4; ++r) {
        int t = t0 + wv * 16 + quad * 4 + r;
        if (t < T_) {
            out[t * 192 + col] = acc0[r];
            out[t * 192 + col + 16] = acc1[r];
        }
    }
}

// ---------- retnet temporal retention: block per (b,n), 256 thr ----------
__global__ __launch_bounds__(256) void k_retnet(const float* __restrict__ qkv,
                                                const float* __restrict__ Dm,
                                                float* __restrict__ att) {
    const int bn = blockIdx.x;           // b*N + n
    const int b = bn / N_, n = bn % N_;
    __shared__ float S[12][192];
    __shared__ float Ds[8 * 145];
    const int tid = threadIdx.x;
    for (int e = tid; e < 12 * 192; e += 256) {
        int p = e / 192, c = e % 192;
        S[p][c] = qkv[((size_t)((b * P_ + p) * N_ + n)) * 192 + c];
    }
    for (int e = tid; e < 1152; e += 256) {
        Ds[(e / 144) * 145 + (e % 144)] = Dm[e];
    }
    __syncthreads();
    const int qq = tid >> 6;
    const int lane = tid & 63;
    const int h = lane >> 3, k = lane & 7;
    for (int q = qq; q < P_; q += 4) {
        float Qv = S[q][h * 8 + k];
        float r[P_];
        float rsum = 0.f;
        #pragma unroll
        for (int p = 0; p < P_; ++p) {
            float prod = Qv * S[p][64 + h * 8 + k];
            prod += __shfl_xor(prod, 1, 64);
            prod += __shfl_xor(prod, 2, 64);
            prod += __shfl_xor(prod, 4, 64);
            float s = (prod / SQRT_DK) * Ds[h * 145 + q * 12 + p];
            r[p] = s; rsum += s;
        }
        float rs = fmaxf(fabsf(rsum), 1.0f);
        float acc = 0.f;
        #pragma unroll
        for (int p = 0; p < P_; ++p) acc += (r[p] / rs) * S[p][128 + h * 8 + k];
        att[((size_t)((b * P_ + q) * N_ + n)) * 64 + lane] = acc;
    }
}

// ---------- temporal enc-dec attention ----------
__global__ __launch_bounds__(256) void k_temporal(const float* __restrict__ qkv,
                                                  float* __restrict__ att) {
    const int bn = blockIdx.x;
    const int b = bn / N_, n = bn % N_;
    __shared__ float S[12][192];
    const int tid = threadIdx.x;
    for (int e = tid; e < 12 * 192; e += 256) {
        int p = e / 192, c = e % 192;
        S[p][c] = qkv[((size_t)((b * P_ + p) * N_ + n)) * 192 + c];
    }
    __syncthreads();
    const int qq = tid >> 6;
    const int lane = tid & 63;
    const int h = lane >> 3, k = lane & 7;
    for (int q = qq; q < P_; q += 4) {
        float Qv = S[q][h * 8 + k];
        float s[P_];
        float mx = -1e30f;
        #pragma unroll
        for (int p = 0; p < P_; ++p) {
            float prod = Qv * S[p][64 + h * 8 + k];
            prod += __shfl_xor(prod, 1, 64);
            prod += __shfl_xor(prod, 2, 64);
            prod += __shfl_xor(prod, 4, 64);
            float v = prod / SQRT_DK;
            s[p] = v; mx = fmaxf(mx, v);
        }
        float den = 0.f, acc = 0.f;
        #pragma unroll
        for (int p = 0; p < P_; ++p) {
            float e = expf(s[p] - mx);
            den += e;
            acc += e * S[p][128 + h * 8 + k];
        }
        att[((size_t)((b * P_ + q) * N_ + n)) * 64 + lane] = acc / den;
    }
}

// ---------- spatial attention v4: block (bp, h, g*4+ichunk); lanes span j ----------
// K transposed in LDS (conflict-free dot), rows split 4-ways across blocks for
// occupancy. nozero-softmax semantics preserved.
__global__ __launch_bounds__(256) void k_spatial4(
    const float* __restrict__ qkvA, const float* __restrict__ qkvB,
    const float* __restrict__ Tm, const float* __restrict__ Am,
    float* __restrict__ attA, float* __restrict__ attB) {
    const int bp = blockIdx.x;          // 0..23
    const int h = blockIdx.y;           // 0..7
    const int g = blockIdx.z >> 2;      // 0,1
    const int ic = blockIdx.z & 3;      // i-chunk
    const float* qkv = g ? qkvB : qkvA;
    float* att = g ? attB : attA;

    __shared__ float sKt[8][192];       // [k][j] transposed
    __shared__ float sV[192][8];        // [j][k]
    __shared__ float sW[4][192];

    const int tid = threadIdx.x;
    for (int e = tid; e < 384; e += 256) {
        int j = e >> 1, kh = (e & 1) * 4;
        float4v k4 = {0.f, 0.f, 0.f, 0.f}, v4 = k4;
        if (j < N_) {
            const float* row = qkv + (size_t)(bp * N_ + j) * 192 + h * 8 + kh;
            k4 = *(const float4v*)(row + 64);
            v4 = *(const float4v*)(row + 128);
        }
        sKt[kh + 0][j] = k4.x;
        sKt[kh + 1][j] = k4.y;
        sKt[kh + 2][j] = k4.z;
        sKt[kh + 3][j] = k4.w;
        *(float4v*)&sV[j][kh] = v4;
    }
    __syncthreads();

    const int wv = tid >> 6;
    const int lane = tid & 63;
    const int j8 = lane >> 3, kk = lane & 7;

    const int i0 = ic * 43;
    const int i1 = (i0 + 43 < N_) ? (i0 + 43) : N_;

    for (int i = i0 + wv; i < i1; i += 4) {
        const float* qrow = qkv + (size_t)(bp * N_ + i) * 192 + h * 8;
        float4v qa = *(const float4v*)qrow;       // uniform: broadcast
        float4v qb = *(const float4v*)(qrow + 4);
        float Qi[8] = {qa.x, qa.y, qa.z, qa.w, qb.x, qb.y, qb.z, qb.w};
        const float* Trow = g ? (Am + (size_t)(bp * N_ + i) * N_) : (Tm + (size_t)i * N_);

        float sloc[3], tloc[3];
        float mx = -1e30f;
        #pragma unroll
        for (int c = 0; c < 3; ++c) {
            int j = c * 64 + lane;
            float tv = 0.f, s = -1e30f;
            if (j < N_) {
                tv = Trow[j];
                if (tv != 0.f) {
                    float dot = 0.f;
                    #pragma unroll
                    for (int k = 0; k < 8; ++k) dot += Qi[k] * sKt[k][j];
                    s = dot / SQRT_DK;
                } else {
                    s = 0.f;   // masked entries are exact zeros and DO enter the max
                }
            }
            sloc[c] = s; tloc[c] = tv;
            mx = fmaxf(mx, s);
        }
        #pragma unroll
        for (int off = 1; off < 64; off <<= 1) mx = fmaxf(mx, __shfl_xor(mx, off, 64));

        float den = 0.f;
        #pragma unroll
        for (int c = 0; c < 3; ++c) {
            float s = sloc[c];
            float e = (s != 0.f) ? expf(s - mx) : 0.f;  // j>=N_: s=-1e30 -> e==0
            den += e;
            sW[wv][c * 64 + lane] = e * tloc[c];
        }
        #pragma unroll
        for (int off = 1; off < 64; off <<= 1) den += __shfl_xor(den, off, 64);

        // PV: lane (j8,kk): partial over j ≡ j8 (mod 8); sW/sV rows >=N_ are 0
        float acc = 0.f;
        #pragma unroll 4
        for (int j = j8; j < 192; j += 8) acc += sW[wv][j] * sV[j][kk];
        acc += __shfl_xor(acc, 8, 64);
        acc += __shfl_xor(acc, 16, 64);
        acc += __shfl_xor(acc, 32, 64);
        if (lane < 8)
            att[(size_t)(bp * N_ + i) * 64 + h * 8 + lane] = acc / (den + 1e-5f);
    }
}

// ---------- gdc over G=8,C=8 for one output dim ----------
__device__ __forceinline__ float gdc8(const float* dv, const float* W1,
                                      const float* W2, int dm) {
    float a[8], s[8];
    #pragma unroll
    for (int g = 0; g < 8; ++g) {
        float aa = 0.f, ss = 0.f;
        #pragma unroll
        for (int c = 0; c < 8; ++c) {
            float d = dv[g * 8 + c];
            aa += d * W1[(g * 8 + c) * 64 + dm];
            ss += d * W2[(g * 8 + c) * 64 + dm];
        }
        a[g] = aa; s[g] = fmaxf(ss, 0.f);
    }
    float mx = s[0];
    #pragma unroll
    for (int g = 1; g < 8; ++g) mx = fmaxf(mx, s[g]);
    float den = 0.f, o = 0.f;
    #pragma unroll
    for (int g = 0; g < 8; ++g) { float e = expf(s[g] - mx); den += e; o += a[g] * e; }
    return o / den;
}

__device__ __forceinline__ float ln_out(float r, int dm, const float* g, const float* b) {
    float m = r, m2 = r * r;
    #pragma unroll
    for (int off = 32; off; off >>= 1) { m += __shfl_xor(m, off, 64); m2 += __shfl_xor(m2, off, 64); }
    m *= (1.f / 64.f); m2 *= (1.f / 64.f);
    float var = m2 - m * m;
    return (r - m) * rsqrtf(var + 1e-5f) * g[dm] + b[dm];
}

// ---------- fused gdc(H=8) + swish-gate + residual + LN ----------
__global__ __launch_bounds__(64) void k_gsl(const float* __restrict__ att, const float* __restrict__ xin,
    const float* W1, const float* W2,
    const float* wg, const float* bg,
    const float* wo, const float* bo,
    const float* lng, const float* lnb, float* __restrict__ xout) {
    int t = blockIdx.x, dm = threadIdx.x;
    __shared__ float dv[64], xv[64], swv[64];
    dv[dm] = att[t * 64 + dm];
    xv[dm] = xin[t * 64 + dm];
    __syncthreads();
    float o = gdc8(dv, W1, W2, dm);
    float hg = bg[dm];
    #pragma unroll
    for (int d = 0; d < 64; ++d) hg += xv[d] * wg[d * 64 + dm];
    hg *= o;
    swv[dm] = hg / (1.f + expf(-hg));
    __syncthreads();
    float ov = bo[dm];
    #pragma unroll
    for (int d = 0; d < 64; ++d) ov += swv[d] * wo[d * 64 + dm];
    float r = ov + xv[dm];
    xout[t * 64 + dm] = ln_out(r, dm, lng, lnb);
}

// ---------- spatial stage tail: gdc0 + gdc1 + g2(G=2,C=64) + swish + LN ----------
__global__ __launch_bounds__(64) void k_spatial_fuse(
    const float* __restrict__ att0, const float* __restrict__ att1, const float* __restrict__ x1,
    const float* gs0_W1, const float* gs0_W2,
    const float* gs1_W1, const float* gs1_W2,
    const float* g2_W1, const float* g2_W2,
    const float* wg, const float* bg,
    const float* wo, const float* bo,
    const float* lng, const float* lnb, float* __restrict__ xout) {
    int t = blockIdx.x, dm = threadIdx.x;
    __shared__ float d0[64], d1[64], o0s[64], o1s[64], xv[64], swv[64];
    d0[dm] = att0[t * 64 + dm];
    d1[dm] = att1[t * 64 + dm];
    xv[dm] = x1[t * 64 + dm];
    __syncthreads();
    o0s[dm] = gdc8(d0, gs0_W1, gs0_W2, dm);
    o1s[dm] = gdc8(d1, gs1_W1, gs1_W2, dm);
    __syncthreads();
    float a0 = 0.f, s0 = 0.f, a1 = 0.f, s1 = 0.f;
    #pragma unroll
    for (int c = 0; c < 64; ++c) {
        a0 += o0s[c] * g2_W1[c * 64 + dm];
        s0 += o0s[c] * g2_W2[c * 64 + dm];
        a1 += o1s[c] * g2_W1[(64 + c) * 64 + dm];
        s1 += o1s[c] * g2_W2[(64 + c) * 64 + dm];
    }
    s0 = fmaxf(s0, 0.f); s1 = fmaxf(s1, 0.f);
    float mx = fmaxf(s0, s1);
    float e0 = expf(s0 - mx), e1 = expf(s1 - mx);
    float o = (a0 * e0 + a1 * e1) / (e0 + e1);
    float hg = bg[dm];
    #pragma unroll
    for (int d = 0; d < 64; ++d) hg += xv[d] * wg[d * 64 + dm];
    hg *= o;
    swv[dm] = hg / (1.f + expf(-hg));
    __syncthreads();
    float ov = bo[dm];
    #pragma unroll
    for (int d = 0; d < 64; ++d) ov += swv[d] * wo[d * 64 + dm];
    float r = ov + xv[dm];
    xout[t * 64 + dm] = ln_out(r, dm, lng, lnb);
}

// ---------- q/k/v projections for enc-dec stage ----------
__global__ __launch_bounds__(64) void k_qkvproj(const float* __restrict__ x2,
    const float* __restrict__ enc,
    const float* wq, const float* wk, const float* wv,
    float* __restrict__ qkv) {
    int t = blockIdx.x, dm = threadIdx.x;
    __shared__ float xv[64], ev[64];
    xv[dm] = x2[t * 64 + dm];
    ev[dm] = enc[t * 64 + dm];
    __syncthreads();
    float aq = 0.f, ak = 0.f, av = 0.f;
    #pragma unroll
    for (int d = 0; d < 64; ++d) {
        aq += xv[d] * wq[d * 64 + dm];
        ak += ev[d] * wk[d * 64 + dm];
        av += ev[d] * wv[d * 64 + dm];
    }
    qkv[t * 192 + dm] = aq;
    qkv[t * 192 + 64 + dm] = ak;
    qkv[t * 192 + 128 + dm] = av;
}

// ---------- FFN + residual + LN -> fp32 output ----------
__global__ __launch_bounds__(64) void k_ffn(const float* __restrict__ x3,
    const float* w1, const float* b1,
    const float* w2, const float* b2,
    const float* lng, const float* lnb,
    float* __restrict__ out) {
    int t = blockIdx.x, dm = threadIdx.x;
    __shared__ float xv[64], hv[256];
    xv[dm] = x3[t * 64 + dm];
    __syncthreads();
    #pragma unroll
    for (int e = 0; e < 4; ++e) {
        int j = e * 64 + dm;
        float a = b1[j];
        #pragma unroll
        for (int d = 0; d < 64; ++d) a += xv[d] * w1[d * 256 + j];
        hv[j] = fmaxf(a, 0.f);
    }
    __syncthreads();
    float a = b2[dm];
    for (int j = 0; j < 256; ++j) a += hv[j] * w2[j * 64 + dm];
    float r = a + xv[dm];
    out[t * 64 + dm] = ln_out(r, dm, lng, lnb);
}

} // namespace

extern "C" void kernel_launch(void* const* d_in, const int* in_sizes, int n_in,
                              void* d_out, int out_size, void* d_ws, size_t ws_size,
                              hipStream_t stream) {
    (void)in_sizes; (void)n_in; (void)out_size; (void)ws_size;
    const float* x    = (const float*)d_in[0];
    const float* c_x  = (const float*)d_in[1];
    const float* enc  = (const float*)d_in[2];
    const float* Tm   = (const float*)d_in[3];
    const float* Am   = (const float*)d_in[4];
    const float* Dm   = (const float*)d_in[5];
    const float* mr_w1 = (const float*)d_in[6];
    const float* mr_b1 = (const float*)d_in[7];
    const float* mr_w2 = (const float*)d_in[8];
    const float* mr_b2 = (const float*)d_in[9];
    const float* ms0_w1 = (const float*)d_in[10];
    const float* ms0_b1 = (const float*)d_in[11];
    const float* ms0_w2 = (const float*)d_in[12];
    const float* ms0_b2 = (const float*)d_in[13];
    const float* ms1_w1 = (const float*)d_in[14];
    const float* ms1_b1 = (const float*)d_in[15];
    const float* ms1_w2 = (const float*)d_in[16];
    const float* ms1_b2 = (const float*)d_in[17];
    const float* gr_W1 = (const float*)d_in[18];
    const float* gr_W2 = (const float*)d_in[19];
    const float* gs0_W1 = (const float*)d_in[20];
    const float* gs0_W2 = (const float*)d_in[21];
    const float* gs1_W1 = (const float*)d_in[22];
    const float* gs1_W2 = (const float*)d_in[23];
    const float* g2_W1 = (const float*)d_in[24];
    const float* g2_W2 = (const float*)d_in[25];
    const float* ge_W1 = (const float*)d_in[26];
    const float* ge_W2 = (const float*)d_in[27];
    const float* swr_wg = (const float*)d_in[28];
    const float* swr_bg = (const float*)d_in[29];
    const float* swr_wo = (const float*)d_in[30];
    const float* swr_bo = (const float*)d_in[31];
    const float* sws_wg = (const float*)d_in[32];
    const float* sws_bg = (const float*)d_in[33];
    const float* sws_wo = (const float*)d_in[34];
    const float* sws_bo = (const float*)d_in[35];
    const float* swe_wg = (const float*)d_in[36];
    const float* swe_bg = (const float*)d_in[37];
    const float* swe_wo = (const float*)d_in[38];
    const float* swe_bo = (const float*)d_in[39];
    const float* lnr_g = (const float*)d_in[40];
    const float* lnr_b = (const float*)d_in[41];
    const float* lns_g = (const float*)d_in[42];
    const float* lns_b = (const float*)d_in[43];
    const float* lne_g = (const float*)d_in[44];
    const float* lne_b = (const float*)d_in[45];
    const float* lnf_g = (const float*)d_in[46];
    const float* lnf_b = (const float*)d_in[47];
    const float* wq = (const float*)d_in[48];
    const float* wk = (const float*)d_in[49];
    const float* wv = (const float*)d_in[50];
    const float* f_w1 = (const float*)d_in[51];
    const float* f_b1 = (const float*)d_in[52];
    const float* f_w2 = (const float*)d_in[53];
    const float* f_b2 = (const float*)d_in[54];

    // workspace layout (fp32), ~12.5 MB
    float* ws   = (float*)d_ws;
    float* hr   = ws;                 // stage-2 graph0 hr
    float* hr2  = hr   + T_ * DH_;    // stage-2 graph1 hr
    float* qkva = hr2  + T_ * DH_;
    float* qkvb = qkva + T_ * 192;
    float* atta = qkvb + T_ * 192;
    float* attb = atta + T_ * DM_;    // also reused as stage-1 hr buffer
    float* x1f  = attb + T_ * DM_;
    float* x2f  = x1f  + T_ * DM_;
    float* x3f  = x2f  + T_ * DM_;
    float* hr_r = attb;               // consumed before k_spatial4 writes attb

    dim3 g1(128, 6, 1), g2g(128, 6, 2);

    // all three meta-hiddens depend only on c_x — one batched launch
    k_hr3<<<dim3(510, 3), 256, 0, stream>>>(c_x, mr_w1, mr_b1, ms0_w1, ms0_b1,
                                            ms1_w1, ms1_b1, hr_r, hr, hr2);

    // ---- stage 1: retnet retention ----
    k_meta_mfma<<<g1, 128, 0, stream>>>(hr_r, hr_r, x, mr_w2, mr_b2, mr_w2, mr_b2, qkva, qkva);
    k_retnet<<<B_ * N_, 256, 0, stream>>>(qkva, Dm, atta);
    k_gsl<<<T_, 64, 0, stream>>>(atta, x, gr_W1, gr_W2, swr_wg, swr_bg, swr_wo, swr_bo,
                                 lnr_g, lnr_b, x1f);

    // ---- stage 2: spatial (predefined T + adaptive A) ----
    k_meta_mfma<<<g2g, 128, 0, stream>>>(hr, hr2, x1f, ms0_w2, ms0_b2, ms1_w2, ms1_b2,
                                         qkva, qkvb);
    k_spatial4<<<dim3(B_ * P_, H_, 8), 256, 0, stream>>>(qkva, qkvb, Tm, Am, atta, attb);
    k_spatial_fuse<<<T_, 64, 0, stream>>>(atta, attb, x1f, gs0_W1, gs0_W2, gs1_W1, gs1_W2,
                                          g2_W1, g2_W2, sws_wg, sws_bg, sws_wo, sws_bo,
                                          lns_g, lns_b, x2f);

    // ---- stage 3: temporal encoder-decoder attention ----
    k_qkvproj<<<T_, 64, 0, stream>>>(x2f, enc, wq, wk, wv, qkva);
    k_temporal<<<B_ * N_, 256, 0, stream>>>(qkva, atta);
    k_gsl<<<T_, 64, 0, stream>>>(atta, x2f, ge_W1, ge_W2, swe_wg, swe_bg, swe_wo, swe_bo,
                                 lne_g, lne_b, x3f);

    // ---- stage 4: FFN ----
    k_ffn<<<T_, 64, 0, stream>>>(x3f, f_w1, f_b1, f_w2, f_b2, lnf_g, lnf_b, (float*)d_out);
}

// Round 7
// 344.666 us; speedup vs baseline: 3.2102x; 1.1264x over previous
//
#include <hip/hip_runtime.h>
#include <hip/hip_bf16.h>
#include <math.h>

namespace {

constexpr int B_ = 2, P_ = 12, N_ = 170, DM_ = 64, H_ = 8, DK_ = 8, DH_ = 32, DF_ = 256;
constexpr int T_ = B_ * P_ * N_;        // 4080 tokens
constexpr float SQRT_DK = 2.8284271247461903f;

constexpr int NG_ = 12;                 // 192 output cols / 16
constexpr int NC_ = 66;                 // 2112 K / 32
constexpr int WFRAG_G = NG_ * NC_ * 64 * 8;   // shorts per graph = 405504

typedef __attribute__((ext_vector_type(4))) short short4v;
typedef __attribute__((ext_vector_type(8))) short short8v;
typedef __attribute__((ext_vector_type(4))) float float4v;

// float -> bf16 bits, round-to-nearest-even
__device__ __forceinline__ unsigned short f2bf(float x) {
    union { float f; unsigned int u; } c; c.f = x;
    unsigned int r = (c.u + 0x7FFFu + ((c.u >> 16) & 1u)) >> 16;
    return (unsigned short)r;
}

// ---------- meta hidden (x3 batched): hr = relu(c_x @ w1 + b1)  [T_,32] ----------
__global__ void k_hr3(const float* __restrict__ c_x,
                      const float* __restrict__ w1a, const float* __restrict__ b1a,
                      const float* __restrict__ w1b, const float* __restrict__ b1b,
                      const float* __restrict__ w1c, const float* __restrict__ b1c,
                      float* __restrict__ hra, float* __restrict__ hrb,
                      float* __restrict__ hrc) {
    int z = blockIdx.y;
    const float* w1 = z == 0 ? w1a : (z == 1 ? w1b : w1c);
    const float* b1 = z == 0 ? b1a : (z == 1 ? b1b : b1c);
    float* hr = z == 0 ? hra : (z == 1 ? hrb : hrc);
    int idx = blockIdx.x * 256 + threadIdx.x;          // t*32 + j
    if (idx >= T_ * DH_) return;
    int t = idx / DH_, j = idx % DH_;
    float acc = b1[j];
    const float* cx = c_x + t * DM_;
    #pragma unroll
    for (int d = 0; d < DM_; ++d) acc += cx[d] * w1[d * DH_ + j];
    hr[idx] = fmaxf(acc, 0.f);
}

// ---------- one-time w2/b2 -> bf16 B-fragment-linear permute ----------
// Wfrag[g][ng][c][lane][j] = bf16( w2p_g[k, m] ),
//   m = ng*16 + (lane&15), k = c*32 + (lane>>4)*8 + j,
//   w2p[jh*64+d, m] = w2[jh, m*64+d] (jh<32) | b2[m*64+d] (jh==32)
__global__ void k_wconv(const float* __restrict__ w2a, const float* __restrict__ b2a,
                        const float* __restrict__ w2b, const float* __restrict__ b2b,
                        const float* __restrict__ w2c, const float* __restrict__ b2c,
                        unsigned short* __restrict__ Wfrag) {
    int idx = blockIdx.x * 256 + threadIdx.x;   // ((g*12+ng)*66+c)*64 + lane
    if (idx >= 3 * NG_ * NC_ * 64) return;
    int lane = idx & 63;
    int c = (idx >> 6) % NC_;
    int ng = (idx >> 6) / NC_ % NG_;
    int g = idx / (64 * NC_ * NG_);
    const float* w2 = g == 0 ? w2a : (g == 1 ? w2b : w2c);
    const float* b2 = g == 0 ? b2a : (g == 1 ? b2b : b2c);
    int m = ng * 16 + (lane & 15);
    int u = c >> 1;                              // jh
    int d0 = (c & 1) * 32 + (lane >> 4) * 8;
    const float* src = (u < DH_) ? (w2 + u * 12288 + m * 64 + d0) : (b2 + m * 64 + d0);
    short8v o;
    #pragma unroll
    for (int j = 0; j < 8; ++j) o[j] = (short)f2bf(src[j]);
    *(short8v*)(Wfrag + (size_t)idx * 8) = o;
}

// ---------- meta+mhlin GEMM v2: no LDS, no barriers ----------
// Wave owns 16 tokens (g16) x 64 cols (nb*64). x-frag in VGPRs; per k-pair:
// 1 hr load + 16 mul/cvt + 8 B-frag dwordx4 (L2-hot) + 8 MFMA.
__global__ __launch_bounds__(256) void k_meta_gemm2(
    const float* __restrict__ hr0, const float* __restrict__ hr1,
    const float* __restrict__ xin,
    const unsigned short* __restrict__ Wf0, const unsigned short* __restrict__ Wf1,
    float* __restrict__ out0, float* __restrict__ out1) {
    const int bz = blockIdx.z;
    const float* hr = bz ? hr1 : hr0;
    const unsigned short* Wf = bz ? Wf1 : Wf0;
    float* out = bz ? out1 : out0;

    const int tid = threadIdx.x;
    const int wv = tid >> 6, lane = tid & 63;
    const int l15 = lane & 15, quad = lane >> 4;
    const int g16 = blockIdx.x * 4 + wv;
    if (g16 >= 255) return;                      // 255 groups of 16 tokens; no barriers
    const int t = g16 * 16 + l15;
    const int nb = blockIdx.y;                   // 0..2

    // preload x fragments: xr[j] = x[t, quad*8+j], xr[8+j] = x[t, 32+quad*8+j]
    const float* xp = xin + t * 64 + quad * 8;
    float4v xa = *(const float4v*)(xp);
    float4v xb = *(const float4v*)(xp + 4);
    float4v xc = *(const float4v*)(xp + 32);
    float4v xd = *(const float4v*)(xp + 36);
    float xr[16] = {xa.x, xa.y, xa.z, xa.w, xb.x, xb.y, xb.z, xb.w,
                    xc.x, xc.y, xc.z, xc.w, xd.x, xd.y, xd.z, xd.w};

    const float* hrp = hr + t * 32;
    float4v acc[4] = {{0.f,0.f,0.f,0.f},{0.f,0.f,0.f,0.f},
                      {0.f,0.f,0.f,0.f},{0.f,0.f,0.f,0.f}};

    // B-frag base for (ng = nb*4 + q, c, lane): ((ng*66 + c)*64 + lane)*8 shorts
    const unsigned short* wb = Wf + ((size_t)(nb * 4) * NC_ * 64 + lane) * 8;
    const size_t qstride = (size_t)NC_ * 64 * 8;   // ng -> ng+1
    const size_t cstride = 64 * 8;                 // c -> c+1

    for (int u = 0; u < 33; ++u) {
        float hrv = (u < DH_) ? hrp[u] : 1.0f;
        short8v a0, a1;
        #pragma unroll
        for (int j = 0; j < 8; ++j) {
            a0[j] = (short)f2bf(hrv * xr[j]);
            a1[j] = (short)f2bf(hrv * xr[8 + j]);
        }
        const unsigned short* wc = wb + (size_t)(2 * u) * cstride;
        #pragma unroll
        for (int q = 0; q < 4; ++q) {
            short8v b0 = *(const short8v*)(wc + q * qstride);
            short8v b1 = *(const short8v*)(wc + q * qstride + cstride);
            acc[q] = __builtin_amdgcn_mfma_f32_16x16x32_bf16(a0, b0, acc[q], 0, 0, 0);
            acc[q] = __builtin_amdgcn_mfma_f32_16x16x32_bf16(a1, b1, acc[q], 0, 0, 0);
        }
    }

    // D: col=lane&15 (n), row=quad*4+r (token)  [learn_hip m89/m91]
    #pragma unroll
    for (int q = 0; q < 4; ++q) {
        #pragma unroll
        for (int r = 0; r < 4; ++r) {
            int tt = g16 * 16 + quad * 4 + r;
            out[tt * 192 + nb * 64 + q * 16 + l15] = acc[q][r];
        }
    }
}

// ---------- retnet temporal retention: block per (b,n), 256 thr ----------
__global__ __launch_bounds__(256) void k_retnet(const float* __restrict__ qkv,
                                                const float* __restrict__ Dm,
                                                float* __restrict__ att) {
    const int bn = blockIdx.x;           // b*N + n
    const int b = bn / N_, n = bn % N_;
    __shared__ float S[12][192];
    __shared__ float Ds[8 * 145];
    const int tid = threadIdx.x;
    for (int e = tid; e < 12 * 192; e += 256) {
        int p = e / 192, c = e % 192;
        S[p][c] = qkv[((size_t)((b * P_ + p) * N_ + n)) * 192 + c];
    }
    for (int e = tid; e < 1152; e += 256) {
        Ds[(e / 144) * 145 + (e % 144)] = Dm[e];
    }
    __syncthreads();
    const int qq = tid >> 6;
    const int lane = tid & 63;
    const int h = lane >> 3, k = lane & 7;
    for (int q = qq; q < P_; q += 4) {
        float Qv = S[q][h * 8 + k];
        float r[P_];
        float rsum = 0.f;
        #pragma unroll
        for (int p = 0; p < P_; ++p) {
            float prod = Qv * S[p][64 + h * 8 + k];
            prod += __shfl_xor(prod, 1, 64);
            prod += __shfl_xor(prod, 2, 64);
            prod += __shfl_xor(prod, 4, 64);
            float s = (prod / SQRT_DK) * Ds[h * 145 + q * 12 + p];
            r[p] = s; rsum += s;
        }
        float rs = fmaxf(fabsf(rsum), 1.0f);
        float acc = 0.f;
        #pragma unroll
        for (int p = 0; p < P_; ++p) acc += (r[p] / rs) * S[p][128 + h * 8 + k];
        att[((size_t)((b * P_ + q) * N_ + n)) * 64 + lane] = acc;
    }
}

// ---------- temporal enc-dec attention ----------
__global__ __launch_bounds__(256) void k_temporal(const float* __restrict__ qkv,
                                                  float* __restrict__ att) {
    const int bn = blockIdx.x;
    const int b = bn / N_, n = bn % N_;
    __shared__ float S[12][192];
    const int tid = threadIdx.x;
    for (int e = tid; e < 12 * 192; e += 256) {
        int p = e / 192, c = e % 192;
        S[p][c] = qkv[((size_t)((b * P_ + p) * N_ + n)) * 192 + c];
    }
    __syncthreads();
    const int qq = tid >> 6;
    const int lane = tid & 63;
    const int h = lane >> 3, k = lane & 7;
    for (int q = qq; q < P_; q += 4) {
        float Qv = S[q][h * 8 + k];
        float s[P_];
        float mx = -1e30f;
        #pragma unroll
        for (int p = 0; p < P_; ++p) {
            float prod = Qv * S[p][64 + h * 8 + k];
            prod += __shfl_xor(prod, 1, 64);
            prod += __shfl_xor(prod, 2, 64);
            prod += __shfl_xor(prod, 4, 64);
            float v = prod / SQRT_DK;
            s[p] = v; mx = fmaxf(mx, v);
        }
        float den = 0.f, acc = 0.f;
        #pragma unroll
        for (int p = 0; p < P_; ++p) {
            float e = expf(s[p] - mx);
            den += e;
            acc += e * S[p][128 + h * 8 + k];
        }
        att[((size_t)((b * P_ + q) * N_ + n)) * 64 + lane] = acc / den;
    }
}

// ---------- spatial attention v4: block (bp, h, g*4+ichunk); lanes span j ----------
__global__ __launch_bounds__(256) void k_spatial4(
    const float* __restrict__ qkvA, const float* __restrict__ qkvB,
    const float* __restrict__ Tm, const float* __restrict__ Am,
    float* __restrict__ attA, float* __restrict__ attB) {
    const int bp = blockIdx.x;          // 0..23
    const int h = blockIdx.y;           // 0..7
    const int g = blockIdx.z >> 2;      // 0,1
    const int ic = blockIdx.z & 3;      // i-chunk
    const float* qkv = g ? qkvB : qkvA;
    float* att = g ? attB : attA;

    __shared__ float sKt[8][192];       // [k][j] transposed
    __shared__ float sV[192][8];        // [j][k]
    __shared__ float sW[4][192];

    const int tid = threadIdx.x;
    for (int e = tid; e < 384; e += 256) {
        int j = e >> 1, kh = (e & 1) * 4;
        float4v k4 = {0.f, 0.f, 0.f, 0.f}, v4 = k4;
        if (j < N_) {
            const float* row = qkv + (size_t)(bp * N_ + j) * 192 + h * 8 + kh;
            k4 = *(const float4v*)(row + 64);
            v4 = *(const float4v*)(row + 128);
        }
        sKt[kh + 0][j] = k4.x;
        sKt[kh + 1][j] = k4.y;
        sKt[kh + 2][j] = k4.z;
        sKt[kh + 3][j] = k4.w;
        *(float4v*)&sV[j][kh] = v4;
    }
    __syncthreads();

    const int wv = tid >> 6;
    const int lane = tid & 63;
    const int j8 = lane >> 3, kk = lane & 7;

    const int i0 = ic * 43;
    const int i1 = (i0 + 43 < N_) ? (i0 + 43) : N_;

    for (int i = i0 + wv; i < i1; i += 4) {
        const float* qrow = qkv + (size_t)(bp * N_ + i) * 192 + h * 8;
        float4v qa = *(const float4v*)qrow;       // uniform: broadcast
        float4v qb = *(const float4v*)(qrow + 4);
        float Qi[8] = {qa.x, qa.y, qa.z, qa.w, qb.x, qb.y, qb.z, qb.w};
        const float* Trow = g ? (Am + (size_t)(bp * N_ + i) * N_) : (Tm + (size_t)i * N_);

        float sloc[3], tloc[3];
        float mx = -1e30f;
        #pragma unroll
        for (int c = 0; c < 3; ++c) {
            int j = c * 64 + lane;
            float tv = 0.f, s = -1e30f;
            if (j < N_) {
                tv = Trow[j];
                if (tv != 0.f) {
                    float dot = 0.f;
                    #pragma unroll
                    for (int k = 0; k < 8; ++k) dot += Qi[k] * sKt[k][j];
                    s = dot / SQRT_DK;
                } else {
                    s = 0.f;   // masked entries are exact zeros and DO enter the max
                }
            }
            sloc[c] = s; tloc[c] = tv;
            mx = fmaxf(mx, s);
        }
        #pragma unroll
        for (int off = 1; off < 64; off <<= 1) mx = fmaxf(mx, __shfl_xor(mx, off, 64));

        float den = 0.f;
        #pragma unroll
        for (int c = 0; c < 3; ++c) {
            float s = sloc[c];
            float e = (s != 0.f) ? expf(s - mx) : 0.f;  // j>=N_: s=-1e30 -> e==0
            den += e;
            sW[wv][c * 64 + lane] = e * tloc[c];
        }
        #pragma unroll
        for (int off = 1; off < 64; off <<= 1) den += __shfl_xor(den, off, 64);

        // PV: lane (j8,kk): partial over j ≡ j8 (mod 8); sW/sV rows >=N_ are 0
        float acc = 0.f;
        #pragma unroll 4
        for (int j = j8; j < 192; j += 8) acc += sW[wv][j] * sV[j][kk];
        acc += __shfl_xor(acc, 8, 64);
        acc += __shfl_xor(acc, 16, 64);
        acc += __shfl_xor(acc, 32, 64);
        if (lane < 8)
            att[(size_t)(bp * N_ + i) * 64 + h * 8 + lane] = acc / (den + 1e-5f);
    }
}

// ---------- gdc over G=8,C=8 for one output dim ----------
__device__ __forceinline__ float gdc8(const float* dv, const float* W1,
                                      const float* W2, int dm) {
    float a[8], s[8];
    #pragma unroll
    for (int g = 0; g < 8; ++g) {
        float aa = 0.f, ss = 0.f;
        #pragma unroll
        for (int c = 0; c < 8; ++c) {
            float d = dv[g * 8 + c];
            aa += d * W1[(g * 8 + c) * 64 + dm];
            ss += d * W2[(g * 8 + c) * 64 + dm];
        }
        a[g] = aa; s[g] = fmaxf(ss, 0.f);
    }
    float mx = s[0];
    #pragma unroll
    for (int g = 1; g < 8; ++g) mx = fmaxf(mx, s[g]);
    float den = 0.f, o = 0.f;
    #pragma unroll
    for (int g = 0; g < 8; ++g) { float e = expf(s[g] - mx); den += e; o += a[g] * e; }
    return o / den;
}

__device__ __forceinline__ float ln_out(float r, int dm, const float* g, const float* b) {
    float m = r, m2 = r * r;
    #pragma unroll
    for (int off = 32; off; off >>= 1) { m += __shfl_xor(m, off, 64); m2 += __shfl_xor(m2, off, 64); }
    m *= (1.f / 64.f); m2 *= (1.f / 64.f);
    float var = m2 - m * m;
    return (r - m) * rsqrtf(var + 1e-5f) * g[dm] + b[dm];
}

// ---------- fused gdc(H=8) + swish-gate + residual + LN ----------
__global__ __launch_bounds__(64) void k_gsl(const float* __restrict__ att, const float* __restrict__ xin,
    const float* W1, const float* W2,
    const float* wg, const float* bg,
    const float* wo, const float* bo,
    const float* lng, const float* lnb, float* __restrict__ xout) {
    int t = blockIdx.x, dm = threadIdx.x;
    __shared__ float dv[64], xv[64], swv[64];
    dv[dm] = att[t * 64 + dm];
    xv[dm] = xin[t * 64 + dm];
    __syncthreads();
    float o = gdc8(dv, W1, W2, dm);
    float hg = bg[dm];
    #pragma unroll
    for (int d = 0; d < 64; ++d) hg += xv[d] * wg[d * 64 + dm];
    hg *= o;
    swv[dm] = hg / (1.f + expf(-hg));
    __syncthreads();
    float ov = bo[dm];
    #pragma unroll
    for (int d = 0; d < 64; ++d) ov += swv[d] * wo[d * 64 + dm];
    float r = ov + xv[dm];
    xout[t * 64 + dm] = ln_out(r, dm, lng, lnb);
}

// ---------- spatial stage tail: gdc0 + gdc1 + g2(G=2,C=64) + swish + LN ----------
__global__ __launch_bounds__(64) void k_spatial_fuse(
    const float* __restrict__ att0, const float* __restrict__ att1, const float* __restrict__ x1,
    const float* gs0_W1, const float* gs0_W2,
    const float* gs1_W1, const float* gs1_W2,
    const float* g2_W1, const float* g2_W2,
    const float* wg, const float* bg,
    const float* wo, const float* bo,
    const float* lng, const float* lnb, float* __restrict__ xout) {
    int t = blockIdx.x, dm = threadIdx.x;
    __shared__ float d0[64], d1[64], o0s[64], o1s[64], xv[64], swv[64];
    d0[dm] = att0[t * 64 + dm];
    d1[dm] = att1[t * 64 + dm];
    xv[dm] = x1[t * 64 + dm];
    __syncthreads();
    o0s[dm] = gdc8(d0, gs0_W1, gs0_W2, dm);
    o1s[dm] = gdc8(d1, gs1_W1, gs1_W2, dm);
    __syncthreads();
    float a0 = 0.f, s0 = 0.f, a1 = 0.f, s1 = 0.f;
    #pragma unroll
    for (int c = 0; c < 64; ++c) {
        a0 += o0s[c] * g2_W1[c * 64 + dm];
        s0 += o0s[c] * g2_W2[c * 64 + dm];
        a1 += o1s[c] * g2_W1[(64 + c) * 64 + dm];
        s1 += o1s[c] * g2_W2[(64 + c) * 64 + dm];
    }
    s0 = fmaxf(s0, 0.f); s1 = fmaxf(s1, 0.f);
    float mx = fmaxf(s0, s1);
    float e0 = expf(s0 - mx), e1 = expf(s1 - mx);
    float o = (a0 * e0 + a1 * e1) / (e0 + e1);
    float hg = bg[dm];
    #pragma unroll
    for (int d = 0; d < 64; ++d) hg += xv[d] * wg[d * 64 + dm];
    hg *= o;
    swv[dm] = hg / (1.f + expf(-hg));
    __syncthreads();
    float ov = bo[dm];
    #pragma unroll
    for (int d = 0; d < 64; ++d) ov += swv[d] * wo[d * 64 + dm];
    float r = ov + xv[dm];
    xout[t * 64 + dm] = ln_out(r, dm, lng, lnb);
}

// ---------- q/k/v projections for enc-dec stage ----------
__global__ __launch_bounds__(64) void k_qkvproj(const float* __restrict__ x2,
    const float* __restrict__ enc,
    const float* wq, const float* wk, const float* wv,
    float* __restrict__ qkv) {
    int t = blockIdx.x, dm = threadIdx.x;
    __shared__ float xv[64], ev[64];
    xv[dm] = x2[t * 64 + dm];
    ev[dm] = enc[t * 64 + dm];
    __syncthreads();
    float aq = 0.f, ak = 0.f, av = 0.f;
    #pragma unroll
    for (int d = 0; d < 64; ++d) {
        aq += xv[d] * wq[d * 64 + dm];
        ak += ev[d] * wk[d * 64 + dm];
        av += ev[d] * wv[d * 64 + dm];
    }
    qkv[t * 192 + dm] = aq;
    qkv[t * 192 + 64 + dm] = ak;
    qkv[t * 192 + 128 + dm] = av;
}

// ---------- FFN + residual + LN -> fp32 output ----------
__global__ __launch_bounds__(64) void k_ffn(const float* __restrict__ x3,
    const float* w1, const float* b1,
    const float* w2, const float* b2,
    const float* lng, const float* lnb,
    float* __restrict__ out) {
    int t = blockIdx.x, dm = threadIdx.x;
    __shared__ float xv[64], hv[256];
    xv[dm] = x3[t * 64 + dm];
    __syncthreads();
    #pragma unroll
    for (int e = 0; e < 4; ++e) {
        int j = e * 64 + dm;
        float a = b1[j];
        #pragma unroll
        for (int d = 0; d < 64; ++d) a += xv[d] * w1[d * 256 + j];
        hv[j] = fmaxf(a, 0.f);
    }
    __syncthreads();
    float a = b2[dm];
    for (int j = 0; j < 256; ++j) a += hv[j] * w2[j * 64 + dm];
    float r = a + xv[dm];
    out[t * 64 + dm] = ln_out(r, dm, lng, lnb);
}

} // namespace

extern "C" void kernel_launch(void* const* d_in, const int* in_sizes, int n_in,
                              void* d_out, int out_size, void* d_ws, size_t ws_size,
                              hipStream_t stream) {
    (void)in_sizes; (void)n_in; (void)out_size; (void)ws_size;
    const float* x    = (const float*)d_in[0];
    const float* c_x  = (const float*)d_in[1];
    const float* enc  = (const float*)d_in[2];
    const float* Tm   = (const float*)d_in[3];
    const float* Am   = (const float*)d_in[4];
    const float* Dm   = (const float*)d_in[5];
    const float* mr_w1 = (const float*)d_in[6];
    const float* mr_b1 = (const float*)d_in[7];
    const float* mr_w2 = (const float*)d_in[8];
    const float* mr_b2 = (const float*)d_in[9];
    const float* ms0_w1 = (const float*)d_in[10];
    const float* ms0_b1 = (const float*)d_in[11];
    const float* ms0_w2 = (const float*)d_in[12];
    const float* ms0_b2 = (const float*)d_in[13];
    const float* ms1_w1 = (const float*)d_in[14];
    const float* ms1_b1 = (const float*)d_in[15];
    const float* ms1_w2 = (const float*)d_in[16];
    const float* ms1_b2 = (const float*)d_in[17];
    const float* gr_W1 = (const float*)d_in[18];
    const float* gr_W2 = (const float*)d_in[19];
    const float* gs0_W1 = (const float*)d_in[20];
    const float* gs0_W2 = (const float*)d_in[21];
    const float* gs1_W1 = (const float*)d_in[22];
    const float* gs1_W2 = (const float*)d_in[23];
    const float* g2_W1 = (const float*)d_in[24];
    const float* g2_W2 = (const float*)d_in[25];
    const float* ge_W1 = (const float*)d_in[26];
    const float* ge_W2 = (const float*)d_in[27];
    const float* swr_wg = (const float*)d_in[28];
    const float* swr_bg = (const float*)d_in[29];
    const float* swr_wo = (const float*)d_in[30];
    const float* swr_bo = (const float*)d_in[31];
    const float* sws_wg = (const float*)d_in[32];
    const float* sws_bg = (const float*)d_in[33];
    const float* sws_wo = (const float*)d_in[34];
    const float* sws_bo = (const float*)d_in[35];
    const float* swe_wg = (const float*)d_in[36];
    const float* swe_bg = (const float*)d_in[37];
    const float* swe_wo = (const float*)d_in[38];
    const float* swe_bo = (const float*)d_in[39];
    const float* lnr_g = (const float*)d_in[40];
    const float* lnr_b = (const float*)d_in[41];
    const float* lns_g = (const float*)d_in[42];
    const float* lns_b = (const float*)d_in[43];
    const float* lne_g = (const float*)d_in[44];
    const float* lne_b = (const float*)d_in[45];
    const float* lnf_g = (const float*)d_in[46];
    const float* lnf_b = (const float*)d_in[47];
    const float* wq = (const float*)d_in[48];
    const float* wk = (const float*)d_in[49];
    const float* wv = (const float*)d_in[50];
    const float* f_w1 = (const float*)d_in[51];
    const float* f_b1 = (const float*)d_in[52];
    const float* f_w2 = (const float*)d_in[53];
    const float* f_b2 = (const float*)d_in[54];

    // workspace layout (~16.2 MB)
    float* ws   = (float*)d_ws;
    float* hr   = ws;                 // stage-2 graph0 hr
    float* hr2  = hr   + T_ * DH_;    // stage-2 graph1 hr
    float* qkva = hr2  + T_ * DH_;
    float* qkvb = qkva + T_ * 192;
    float* atta = qkvb + T_ * 192;
    float* attb = atta + T_ * DM_;    // also reused as stage-1 hr buffer
    float* x1f  = attb + T_ * DM_;
    float* x2f  = x1f  + T_ * DM_;
    float* x3f  = x2f  + T_ * DM_;
    unsigned short* Wfrag = (unsigned short*)(x3f + T_ * DM_);  // 3 graphs, 2.4 MB
    float* hr_r = attb;               // consumed before k_spatial4 writes attb

    // one-time permute of all three w2/b2 into bf16 B-fragment layout
    k_wconv<<<(3 * NG_ * NC_ * 64 + 255) / 256, 256, 0, stream>>>(
        mr_w2, mr_b2, ms0_w2, ms0_b2, ms1_w2, ms1_b2, Wfrag);

    // all three meta-hiddens depend only on c_x — one batched launch
    k_hr3<<<dim3(510, 3), 256, 0, stream>>>(c_x, mr_w1, mr_b1, ms0_w1, ms0_b1,
                                            ms1_w1, ms1_b1, hr_r, hr, hr2);

    // ---- stage 1: retnet retention ----
    k_meta_gemm2<<<dim3(64, 3, 1), 256, 0, stream>>>(
        hr_r, hr_r, x, Wfrag, Wfrag, qkva, qkva);
    k_retnet<<<B_ * N_, 256, 0, stream>>>(qkva, Dm, atta);
    k_gsl<<<T_, 64, 0, stream>>>(atta, x, gr_W1, gr_W2, swr_wg, swr_bg, swr_wo, swr_bo,
                                 lnr_g, lnr_b, x1f);

    // ---- stage 2: spatial (predefined T + adaptive A) ----
    k_meta_gemm2<<<dim3(64, 3, 2), 256, 0, stream>>>(
        hr, hr2, x1f, Wfrag + WFRAG_G, Wfrag + 2 * WFRAG_G, qkva, qkvb);
    k_spatial4<<<dim3(B_ * P_, H_, 8), 256, 0, stream>>>(qkva, qkvb, Tm, Am, atta, attb);
    k_spatial_fuse<<<T_, 64, 0, stream>>>(atta, attb, x1f, gs0_W1, gs0_W2, gs1_W1, gs1_W2,
                                          g2_W1, g2_W2, sws_wg, sws_bg, sws_wo, sws_bo,
                                          lns_g, lns_b, x2f);

    // ---- stage 3: temporal encoder-decoder attention ----
    k_qkvproj<<<T_, 64, 0, stream>>>(x2f, enc, wq, wk, wv, qkva);
    k_temporal<<<B_ * N_, 256, 0, stream>>>(qkva, atta);
    k_gsl<<<T_, 64, 0, stream>>>(atta, x2f, ge_W1, ge_W2, swe_wg, swe_bg, swe_wo, swe_bo,
                                 lne_g, lne_b, x3f);

    // ---- stage 4: FFN ----
    k_ffn<<<T_, 64, 0, stream>>>(x3f, f_w1, f_b1, f_w2, f_b2, lnf_g, lnf_b, (float*)d_out);
}